// Round 1
// baseline (12681.602 us; speedup 1.0000x reference)
//
#include <hip/hip_runtime.h>
#include <hip/hip_bf16.h>

#define N_NODES  50000
#define N_EDGES  800000
#define N_GRAPHS 512

// ---- workspace layout (float offsets) ----
// zeroed region:
constexpr size_t AGG1 = 0;                      // [N][96]   (3 convs x 32)
constexpr size_t AGG2 = AGG1 + (size_t)N_NODES * 96;   // [N][192]  (3 convs x 64)
constexpr size_t GSUM = AGG2 + (size_t)N_NODES * 192;  // [G][64]
constexpr size_t GCNT = GSUM + (size_t)N_GRAPHS * 64;  // [G]
constexpr size_t ZERO_FLOATS = GCNT + N_GRAPHS;
// overwritten-every-call region:
constexpr size_t H1   = ZERO_FLOATS;                   // [N][64]
constexpr size_t V1H  = H1 + (size_t)N_NODES * 64;     // [64][96]  folded em1_w2 @ c1_lin_w
constexpr size_t B1F  = V1H + 64 * 96;                 // [96]
constexpr size_t V2H  = B1F + 96;                      // [64][192] folded em2_w2 @ c2_lin_w
constexpr size_t B2F  = V2H + 64 * 192;                // [192]
constexpr size_t U1   = B2F + 192;                     // [3][64][64] folded c1_w2 @ lin1 block
constexpr size_t UB1  = U1 + 3 * 64 * 64;              // [64]
constexpr size_t U2   = UB1 + 64;                      // [3][64][64] folded c2_w2 @ lin2 block
constexpr size_t UB2  = U2 + 3 * 64 * 64;              // [64]
constexpr size_t W1T1 = UB2 + 64;                      // [3][64][32] c1_w1 transposed (j-major)
constexpr size_t W1T2 = W1T1 + 3 * 64 * 32;            // [3][64][64] c2_w1 transposed
constexpr size_t WS_TOTAL = W1T2 + 3 * 64 * 64;        // ~70.8 MB

// fold region sizes
constexpr int FV1H = 64 * 96, FB1F = 96, FV2H = 64 * 192, FB2F = 192;
constexpr int FU   = 3 * 64 * 64, FUB = 64, FW1T1 = 3 * 64 * 32, FW1T2 = 3 * 64 * 64;
constexpr int FOLD_TOTAL = FV1H + FB1F + FV2H + FB2F + FU + FUB + FU + FUB + FW1T1 + FW1T2;

// ---------------- fold: precompute folded weight products ----------------
__global__ __launch_bounds__(256) void fold_kernel(
    const float* __restrict__ em1_w2, const float* __restrict__ em1_b2,
    const float* __restrict__ em2_w2, const float* __restrict__ em2_b2,
    const float* __restrict__ c1_lin_w, const float* __restrict__ c1_lin_b,
    const float* __restrict__ c2_lin_w, const float* __restrict__ c2_lin_b,
    const float* __restrict__ c1_w1, const float* __restrict__ c2_w1,
    const float* __restrict__ c1_w2, const float* __restrict__ c1_b2,
    const float* __restrict__ c2_w2, const float* __restrict__ c2_b2,
    const float* __restrict__ lin1_w, const float* __restrict__ lin1_b,
    const float* __restrict__ lin2_w, const float* __restrict__ lin2_b,
    float* __restrict__ ws)
{
    int idx = blockIdx.x * 256 + threadIdx.x;
    if (idx >= FOLD_TOTAL) return;

    if (idx < FV1H) {                      // V1H[k][i*32+j] = sum_m em1_w2[k][m]*c1_lin_w[i][m][j]
        int k = idx / 96, c = idx % 96, i = c / 32, j = c % 32;
        float s = 0.f;
        for (int m = 0; m < 64; m++) s = fmaf(em1_w2[k * 64 + m], c1_lin_w[i * 2048 + m * 32 + j], s);
        ws[V1H + idx] = s; return;
    }
    idx -= FV1H;
    if (idx < FB1F) {                      // B1F = em1_b2 @ c1_lin_w + c1_lin_b
        int i = idx / 32, j = idx % 32;
        float s = c1_lin_b[idx];
        for (int m = 0; m < 64; m++) s = fmaf(em1_b2[m], c1_lin_w[i * 2048 + m * 32 + j], s);
        ws[B1F + idx] = s; return;
    }
    idx -= FB1F;
    if (idx < FV2H) {                      // V2H[k][i*64+j]
        int k = idx / 192, c = idx % 192, i = c / 64, j = c % 64;
        float s = 0.f;
        for (int m = 0; m < 64; m++) s = fmaf(em2_w2[k * 64 + m], c2_lin_w[i * 4096 + m * 64 + j], s);
        ws[V2H + idx] = s; return;
    }
    idx -= FV2H;
    if (idx < FB2F) {
        int i = idx / 64, j = idx % 64;
        float s = c2_lin_b[idx];
        for (int m = 0; m < 64; m++) s = fmaf(em2_b2[m], c2_lin_w[i * 4096 + m * 64 + j], s);
        ws[B2F + idx] = s; return;
    }
    idx -= FB2F;
    if (idx < FU) {                        // U1[i][k][j] = sum_m c1_w2[i][k][m]*lin1_w[i*64+m][j]
        int i = idx / 4096, k = (idx / 64) % 64, j = idx % 64;
        float s = 0.f;
        for (int m = 0; m < 64; m++) s = fmaf(c1_w2[i * 4096 + k * 64 + m], lin1_w[(i * 64 + m) * 64 + j], s);
        ws[U1 + idx] = s; return;
    }
    idx -= FU;
    if (idx < FUB) {                       // UB1[j] = sum_{i,m} c1_b2[i][m]*lin1_w[i*64+m][j] + lin1_b[j]
        int j = idx;
        float s = lin1_b[j];
        for (int i = 0; i < 3; i++)
            for (int m = 0; m < 64; m++) s = fmaf(c1_b2[i * 64 + m], lin1_w[(i * 64 + m) * 64 + j], s);
        ws[UB1 + idx] = s; return;
    }
    idx -= FUB;
    if (idx < FU) {                        // U2
        int i = idx / 4096, k = (idx / 64) % 64, j = idx % 64;
        float s = 0.f;
        for (int m = 0; m < 64; m++) s = fmaf(c2_w2[i * 4096 + k * 64 + m], lin2_w[(i * 64 + m) * 64 + j], s);
        ws[U2 + idx] = s; return;
    }
    idx -= FU;
    if (idx < FUB) {                       // UB2
        int j = idx;
        float s = lin2_b[j];
        for (int i = 0; i < 3; i++)
            for (int m = 0; m < 64; m++) s = fmaf(c2_b2[i * 64 + m], lin2_w[(i * 64 + m) * 64 + j], s);
        ws[UB2 + idx] = s; return;
    }
    idx -= FUB;
    if (idx < FW1T1) {                     // W1T1[i][j][k] = c1_w1[i][k][j]
        int i = idx / 2048, j = (idx / 32) % 64, k = idx % 32;
        ws[W1T1 + idx] = c1_w1[i * 2048 + k * 64 + j]; return;
    }
    idx -= FW1T1;
    if (idx < FW1T2) {                     // W1T2[i][j][k] = c2_w1[i][k][j]
        int i = idx / 4096, j = (idx / 64) % 64, k = idx % 64;
        ws[W1T2 + idx] = c2_w1[i * 4096 + k * 64 + j]; return;
    }
}

// ---------------- edge phase 1 ----------------
// per edge: t = relu(ea@em1_w1+b1); for conv i: p = t@V1_i + b; m = relu(x[src]+p); atomic agg1[dst]
__global__ __launch_bounds__(128) void edge1_kernel(
    const float* __restrict__ x, const float* __restrict__ edge_attr,
    const int* __restrict__ ei,
    const float* __restrict__ w1, const float* __restrict__ b1,
    const float* __restrict__ V1h, const float* __restrict__ b1f,
    float* __restrict__ agg1)
{
    __shared__ float ts[64 * 128];   // t transposed: [k][tid] -> conflict-free
    const int tid = threadIdx.x;
    const int e = blockIdx.x * 128 + tid;
    if (e >= N_EDGES) return;
    const int src = ei[e];
    const int dst = ei[N_EDGES + e];

    float t[64];
#pragma unroll
    for (int m = 0; m < 64; m++) t[m] = b1[m];
#pragma unroll
    for (int k4 = 0; k4 < 4; k4++) {
        const float4 a = *(const float4*)(edge_attr + (size_t)e * 16 + k4 * 4);
#pragma unroll
        for (int m = 0; m < 64; m++) t[m] = fmaf(a.x, w1[(k4 * 4 + 0) * 64 + m], t[m]);
#pragma unroll
        for (int m = 0; m < 64; m++) t[m] = fmaf(a.y, w1[(k4 * 4 + 1) * 64 + m], t[m]);
#pragma unroll
        for (int m = 0; m < 64; m++) t[m] = fmaf(a.z, w1[(k4 * 4 + 2) * 64 + m], t[m]);
#pragma unroll
        for (int m = 0; m < 64; m++) t[m] = fmaf(a.w, w1[(k4 * 4 + 3) * 64 + m], t[m]);
    }
#pragma unroll
    for (int m = 0; m < 64; m++) ts[m * 128 + tid] = fmaxf(t[m], 0.f);

    float xs[32];
#pragma unroll
    for (int j4 = 0; j4 < 8; j4++) {
        float4 v = *(const float4*)(x + (size_t)src * 32 + j4 * 4);
        xs[j4 * 4 + 0] = v.x; xs[j4 * 4 + 1] = v.y; xs[j4 * 4 + 2] = v.z; xs[j4 * 4 + 3] = v.w;
    }

    for (int i = 0; i < 3; i++) {
        float p[32];
#pragma unroll
        for (int j = 0; j < 32; j++) p[j] = b1f[i * 32 + j];
        for (int k = 0; k < 64; k++) {
            float tk = ts[k * 128 + tid];
#pragma unroll
            for (int j = 0; j < 32; j++) p[j] = fmaf(tk, V1h[k * 96 + i * 32 + j], p[j]);
        }
#pragma unroll
        for (int j = 0; j < 32; j++) {
            float m = fmaxf(xs[j] + p[j], 0.f);
            atomicAdd(&agg1[(size_t)dst * 96 + i * 32 + j], m);
        }
    }
}

// ---------------- node phase 1 (thread per node) ----------------
__global__ __launch_bounds__(256) void node1_kernel(
    const float* __restrict__ x, const float* __restrict__ agg1,
    const float* __restrict__ w1t, const float* __restrict__ b1,
    const float* __restrict__ U1w, const float* __restrict__ Ub1,
    float* __restrict__ h1)
{
    int n = blockIdx.x * 256 + threadIdx.x;
    if (n >= N_NODES) return;
    float acc[64];
#pragma unroll
    for (int j = 0; j < 64; j++) acc[j] = Ub1[j];
    for (int i = 0; i < 3; i++) {
        float in[32];
#pragma unroll
        for (int k = 0; k < 32; k++) in[k] = x[(size_t)n * 32 + k] + agg1[(size_t)n * 96 + i * 32 + k];
        for (int j = 0; j < 64; j++) {
            float z = b1[i * 64 + j];
#pragma unroll
            for (int k = 0; k < 32; k++) z = fmaf(in[k], w1t[i * 2048 + j * 32 + k], z);
            z = fmaxf(z, 0.f);
#pragma unroll
            for (int jj = 0; jj < 64; jj++) acc[jj] = fmaf(z, U1w[i * 4096 + j * 64 + jj], acc[jj]);
        }
    }
#pragma unroll
    for (int j = 0; j < 64; j++) h1[(size_t)n * 64 + j] = fmaxf(acc[j], 0.f);
}

// ---------------- edge phase 2 ----------------
__global__ __launch_bounds__(128) void edge2_kernel(
    const float* __restrict__ h1, const float* __restrict__ edge_attr,
    const int* __restrict__ ei,
    const float* __restrict__ w1, const float* __restrict__ b1,
    const float* __restrict__ V2h, const float* __restrict__ b2f,
    float* __restrict__ agg2)
{
    __shared__ float ts[64 * 128];
    const int tid = threadIdx.x;
    const int e = blockIdx.x * 128 + tid;
    if (e >= N_EDGES) return;
    const int src = ei[e];
    const int dst = ei[N_EDGES + e];

    float t[64];
#pragma unroll
    for (int m = 0; m < 64; m++) t[m] = b1[m];
#pragma unroll
    for (int k4 = 0; k4 < 4; k4++) {
        const float4 a = *(const float4*)(edge_attr + (size_t)e * 16 + k4 * 4);
#pragma unroll
        for (int m = 0; m < 64; m++) t[m] = fmaf(a.x, w1[(k4 * 4 + 0) * 64 + m], t[m]);
#pragma unroll
        for (int m = 0; m < 64; m++) t[m] = fmaf(a.y, w1[(k4 * 4 + 1) * 64 + m], t[m]);
#pragma unroll
        for (int m = 0; m < 64; m++) t[m] = fmaf(a.z, w1[(k4 * 4 + 2) * 64 + m], t[m]);
#pragma unroll
        for (int m = 0; m < 64; m++) t[m] = fmaf(a.w, w1[(k4 * 4 + 3) * 64 + m], t[m]);
    }
#pragma unroll
    for (int m = 0; m < 64; m++) ts[m * 128 + tid] = fmaxf(t[m], 0.f);

    float hs[64];
#pragma unroll
    for (int j4 = 0; j4 < 16; j4++) {
        float4 v = *(const float4*)(h1 + (size_t)src * 64 + j4 * 4);
        hs[j4 * 4 + 0] = v.x; hs[j4 * 4 + 1] = v.y; hs[j4 * 4 + 2] = v.z; hs[j4 * 4 + 3] = v.w;
    }

    for (int i = 0; i < 3; i++) {
        float p[64];
#pragma unroll
        for (int j = 0; j < 64; j++) p[j] = b2f[i * 64 + j];
        for (int k = 0; k < 64; k++) {
            float tk = ts[k * 128 + tid];
#pragma unroll
            for (int j = 0; j < 64; j++) p[j] = fmaf(tk, V2h[k * 192 + i * 64 + j], p[j]);
        }
#pragma unroll
        for (int j = 0; j < 64; j++) {
            float m = fmaxf(hs[j] + p[j], 0.f);
            atomicAdd(&agg2[(size_t)dst * 192 + i * 64 + j], m);
        }
    }
}

// ---------------- node phase 2 + pooling atomics ----------------
__global__ __launch_bounds__(256) void node2_kernel(
    const float* __restrict__ h1, const float* __restrict__ agg2,
    const float* __restrict__ w1t, const float* __restrict__ b1,
    const float* __restrict__ U2w, const float* __restrict__ Ub2,
    const int* __restrict__ batch,
    float* __restrict__ gsum, float* __restrict__ gcnt)
{
    int n = blockIdx.x * 256 + threadIdx.x;
    if (n >= N_NODES) return;
    float acc[64];
#pragma unroll
    for (int j = 0; j < 64; j++) acc[j] = Ub2[j];
    for (int i = 0; i < 3; i++) {
        float in[64];
#pragma unroll
        for (int k = 0; k < 64; k++) in[k] = h1[(size_t)n * 64 + k] + agg2[(size_t)n * 192 + i * 64 + k];
        for (int j = 0; j < 64; j++) {
            float z = b1[i * 64 + j];
#pragma unroll
            for (int k = 0; k < 64; k++) z = fmaf(in[k], w1t[i * 4096 + j * 64 + k], z);
            z = fmaxf(z, 0.f);
#pragma unroll
            for (int jj = 0; jj < 64; jj++) acc[jj] = fmaf(z, U2w[i * 4096 + j * 64 + jj], acc[jj]);
        }
    }
    int g = batch[n];
#pragma unroll
    for (int j = 0; j < 64; j++) atomicAdd(&gsum[(size_t)g * 64 + j], fmaxf(acc[j], 0.f));
    atomicAdd(&gcnt[g], 1.0f);
}

// ---------------- final: mean-pool divide + fc ----------------
__global__ __launch_bounds__(256) void final_kernel(
    const float* __restrict__ gsum, const float* __restrict__ gcnt,
    const float* __restrict__ u, const float* __restrict__ fc_w,
    const float* __restrict__ fc_b, float* __restrict__ out)
{
    int g = blockIdx.x * 256 + threadIdx.x;
    if (g >= N_GRAPHS) return;
    float inv = 1.f / fmaxf(gcnt[g], 1.f);
    float s = fc_b[0];
#pragma unroll
    for (int j = 0; j < 64; j++) s = fmaf(gsum[(size_t)g * 64 + j] * inv, fc_w[j], s);
#pragma unroll
    for (int k = 0; k < 32; k++) s = fmaf(u[(size_t)g * 32 + k], fc_w[64 + k], s);
    out[g] = s;
}

extern "C" void kernel_launch(void* const* d_in, const int* in_sizes, int n_in,
                              void* d_out, int out_size, void* d_ws, size_t ws_size,
                              hipStream_t stream) {
    (void)in_sizes; (void)n_in; (void)out_size; (void)ws_size;
    const float* x        = (const float*)d_in[0];
    const float* edge_attr= (const float*)d_in[1];
    const float* u        = (const float*)d_in[2];
    const float* em1_w1   = (const float*)d_in[3];
    const float* em1_b1   = (const float*)d_in[4];
    const float* em1_w2   = (const float*)d_in[5];
    const float* em1_b2   = (const float*)d_in[6];
    const float* em2_w1   = (const float*)d_in[7];
    const float* em2_b1   = (const float*)d_in[8];
    const float* em2_w2   = (const float*)d_in[9];
    const float* em2_b2   = (const float*)d_in[10];
    const float* c1_lin_w = (const float*)d_in[11];
    const float* c1_lin_b = (const float*)d_in[12];
    const float* c1_w1    = (const float*)d_in[13];
    const float* c1_b1    = (const float*)d_in[14];
    const float* c1_w2    = (const float*)d_in[15];
    const float* c1_b2    = (const float*)d_in[16];
    const float* c2_lin_w = (const float*)d_in[17];
    const float* c2_lin_b = (const float*)d_in[18];
    const float* c2_w1    = (const float*)d_in[19];
    const float* c2_b1    = (const float*)d_in[20];
    const float* c2_w2    = (const float*)d_in[21];
    const float* c2_b2    = (const float*)d_in[22];
    const float* lin1_w   = (const float*)d_in[23];
    const float* lin1_b   = (const float*)d_in[24];
    const float* lin2_w   = (const float*)d_in[25];
    const float* lin2_b   = (const float*)d_in[26];
    const float* fc_w     = (const float*)d_in[27];
    const float* fc_b     = (const float*)d_in[28];
    const int*   ei       = (const int*)d_in[29];
    const int*   batch    = (const int*)d_in[30];
    float* ws  = (float*)d_ws;
    float* out = (float*)d_out;

    // zero accumulators (agg1, agg2, gsum, gcnt)
    hipMemsetAsync(d_ws, 0, ZERO_FLOATS * sizeof(float), stream);

    fold_kernel<<<(FOLD_TOTAL + 255) / 256, 256, 0, stream>>>(
        em1_w2, em1_b2, em2_w2, em2_b2, c1_lin_w, c1_lin_b, c2_lin_w, c2_lin_b,
        c1_w1, c2_w1, c1_w2, c1_b2, c2_w2, c2_b2, lin1_w, lin1_b, lin2_w, lin2_b, ws);

    edge1_kernel<<<N_EDGES / 128, 128, 0, stream>>>(
        x, edge_attr, ei, em1_w1, em1_b1, ws + V1H, ws + B1F, ws + AGG1);

    node1_kernel<<<(N_NODES + 255) / 256, 256, 0, stream>>>(
        x, ws + AGG1, ws + W1T1, c1_b1, ws + U1, ws + UB1, ws + H1);

    edge2_kernel<<<N_EDGES / 128, 128, 0, stream>>>(
        ws + H1, edge_attr, ei, em2_w1, em2_b1, ws + V2H, ws + B2F, ws + AGG2);

    node2_kernel<<<(N_NODES + 255) / 256, 256, 0, stream>>>(
        ws + H1, ws + AGG2, ws + W1T2, c2_b1, ws + U2, ws + UB2, batch,
        ws + GSUM, ws + GCNT);

    final_kernel<<<(N_GRAPHS + 255) / 256, 256, 0, stream>>>(
        ws + GSUM, ws + GCNT, u, fc_w, fc_b, out);
}

// Round 2
// 1725.862 us; speedup vs baseline: 7.3480x; 7.3480x over previous
//
#include <hip/hip_runtime.h>
#include <hip/hip_bf16.h>

#define N_NODES  50000
#define N_EDGES  800000
#define N_GRAPHS 512
#define ECHUNK   400000

// ---------------- workspace layout (BYTE offsets, 256-aligned) ----------------
constexpr size_t B_CNT  = 0;                 // N ints (zeroed)
constexpr size_t B_GSUM = 200192;            // 512*64 f (zeroed)
constexpr size_t B_GCNT = 331264;            // 512 f (zeroed)
constexpr size_t B_AGG2 = 333312;            // N*192 f (zeroed)
constexpr size_t ZERO_BYTES = 38733312;
constexpr size_t B_OFF  = 38733312;          // (N+1) ints
constexpr size_t B_CUR  = 38933504;          // N ints
constexpr size_t B_BSUM = 39133696;          // 256 ints
constexpr size_t B_SSRC = 39134720;          // E ints  (src of sorted edge)
constexpr size_t B_SEID = 42334720;          // E ints  (orig edge id of sorted edge)
constexpr size_t B_Q    = 45534720;          // 153.6 MB bf16 (q1[E][96] | q2[ECHUNK][192])
constexpr size_t B_H1   = 199134720;         // N*64 f
constexpr size_t B_H2   = 211934720;         // N*64 f
constexpr size_t B_FOLD = 224734720;         // folded weights, 43424 floats
// fold-region float offsets
constexpr int F_V1H = 0;      // [64][96]
constexpr int F_B1F = 6144;   // [96]
constexpr int F_V2H = 6240;   // [64][192]
constexpr int F_B2F = 18528;  // [192]
constexpr int F_U1  = 18720;  // [3][64][64]
constexpr int F_UB1 = 31008;  // [64]
constexpr int F_U2  = 31072;  // [3][64][64]
constexpr int F_UB2 = 43360;  // [64]
constexpr int FOLD_TOTAL = 43424;

__device__ inline unsigned int pack2bf(float a, float b) {
    unsigned int ua = __float_as_uint(a), ub = __float_as_uint(b);
    return ((ua + 0x7FFFu + ((ua >> 16) & 1u)) >> 16) |
           ((ub + 0x7FFFu + ((ub >> 16) & 1u)) & 0xFFFF0000u);
}
__device__ inline float bflo(unsigned int u) { return __uint_as_float(u << 16); }
__device__ inline float bfhi(unsigned int u) { return __uint_as_float(u & 0xFFFF0000u); }

// ---------------- fold: precompute folded weight products ----------------
__global__ __launch_bounds__(256) void fold_kernel(
    const float* __restrict__ em1_w2, const float* __restrict__ em1_b2,
    const float* __restrict__ em2_w2, const float* __restrict__ em2_b2,
    const float* __restrict__ c1_lin_w, const float* __restrict__ c1_lin_b,
    const float* __restrict__ c2_lin_w, const float* __restrict__ c2_lin_b,
    const float* __restrict__ c1_w2, const float* __restrict__ c1_b2,
    const float* __restrict__ c2_w2, const float* __restrict__ c2_b2,
    const float* __restrict__ lin1_w, const float* __restrict__ lin1_b,
    const float* __restrict__ lin2_w, const float* __restrict__ lin2_b,
    float* __restrict__ fw)
{
    int idx = blockIdx.x * 256 + threadIdx.x;
    if (idx >= FOLD_TOTAL) return;
    int r = idx;
    if (r < 6144) {                        // V1H[k][i*32+j] = sum_m em1_w2[k][m]*c1_lin_w[i][m][j]
        int k = r / 96, c = r % 96, i = c / 32, j = c % 32;
        float s = 0.f;
        for (int m = 0; m < 64; m++) s = fmaf(em1_w2[k * 64 + m], c1_lin_w[i * 2048 + m * 32 + j], s);
        fw[F_V1H + r] = s; return;
    }
    r -= 6144;
    if (r < 96) {                          // B1F = em1_b2 @ c1_lin_w + c1_lin_b
        int i = r / 32, j = r % 32;
        float s = c1_lin_b[r];
        for (int m = 0; m < 64; m++) s = fmaf(em1_b2[m], c1_lin_w[i * 2048 + m * 32 + j], s);
        fw[F_B1F + r] = s; return;
    }
    r -= 96;
    if (r < 12288) {                       // V2H[k][i*64+j]
        int k = r / 192, c = r % 192, i = c / 64, j = c % 64;
        float s = 0.f;
        for (int m = 0; m < 64; m++) s = fmaf(em2_w2[k * 64 + m], c2_lin_w[i * 4096 + m * 64 + j], s);
        fw[F_V2H + r] = s; return;
    }
    r -= 12288;
    if (r < 192) {
        int i = r / 64, j = r % 64;
        float s = c2_lin_b[r];
        for (int m = 0; m < 64; m++) s = fmaf(em2_b2[m], c2_lin_w[i * 4096 + m * 64 + j], s);
        fw[F_B2F + r] = s; return;
    }
    r -= 192;
    if (r < 12288) {                       // U1[i][k][j] = sum_m c1_w2[i][k][m]*lin1_w[(i*64+m)][j]
        int i = r / 4096, k = (r / 64) % 64, j = r % 64;
        float s = 0.f;
        for (int m = 0; m < 64; m++) s = fmaf(c1_w2[i * 4096 + k * 64 + m], lin1_w[(i * 64 + m) * 64 + j], s);
        fw[F_U1 + r] = s; return;
    }
    r -= 12288;
    if (r < 64) {                          // UB1
        float s = lin1_b[r];
        for (int i = 0; i < 3; i++)
            for (int m = 0; m < 64; m++) s = fmaf(c1_b2[i * 64 + m], lin1_w[(i * 64 + m) * 64 + r], s);
        fw[F_UB1 + r] = s; return;
    }
    r -= 64;
    if (r < 12288) {                       // U2
        int i = r / 4096, k = (r / 64) % 64, j = r % 64;
        float s = 0.f;
        for (int m = 0; m < 64; m++) s = fmaf(c2_w2[i * 4096 + k * 64 + m], lin2_w[(i * 64 + m) * 64 + j], s);
        fw[F_U2 + r] = s; return;
    }
    r -= 12288;
    {                                      // UB2
        float s = lin2_b[r];
        for (int i = 0; i < 3; i++)
            for (int m = 0; m < 64; m++) s = fmaf(c2_b2[i * 64 + m], lin2_w[(i * 64 + m) * 64 + r], s);
        fw[F_UB2 + r] = s; return;
    }
}

// ---------------- counting sort: hist -> scan -> scatter ----------------
__global__ __launch_bounds__(256) void hist_kernel(const int* __restrict__ ei, int* __restrict__ cnt) {
    int e = blockIdx.x * 256 + threadIdx.x;
    if (e < N_EDGES) atomicAdd(&cnt[ei[N_EDGES + e]], 1);
}

__global__ __launch_bounds__(256) void scan1_kernel(const int* __restrict__ cnt,
                                                    int* __restrict__ off, int* __restrict__ bsum) {
    __shared__ int sh[256];
    int t = threadIdx.x, i = blockIdx.x * 256 + t;
    int v = (i < N_NODES) ? cnt[i] : 0;
    sh[t] = v; __syncthreads();
    for (int d = 1; d < 256; d <<= 1) {
        int add = (t >= d) ? sh[t - d] : 0;
        __syncthreads();
        sh[t] += add;
        __syncthreads();
    }
    if (i < N_NODES) off[i] = sh[t] - v;     // exclusive
    if (t == 255) bsum[blockIdx.x] = sh[255];
}

__global__ __launch_bounds__(256) void scan2_kernel(int* __restrict__ bsum) {
    __shared__ int sh[256];
    int t = threadIdx.x;
    int v = (t < 196) ? bsum[t] : 0;
    sh[t] = v; __syncthreads();
    for (int d = 1; d < 256; d <<= 1) {
        int add = (t >= d) ? sh[t - d] : 0;
        __syncthreads();
        sh[t] += add;
        __syncthreads();
    }
    bsum[t] = sh[t] - v;                      // exclusive
}

__global__ __launch_bounds__(256) void scan3_kernel(int* __restrict__ off, const int* __restrict__ bsum,
                                                    int* __restrict__ cur) {
    int i = blockIdx.x * 256 + threadIdx.x;
    if (i < N_NODES) {
        int o = off[i] + bsum[i >> 8];
        off[i] = o;
        cur[i] = o;
    }
    if (i == 0) off[N_NODES] = N_EDGES;
}

__global__ __launch_bounds__(256) void scatter_kernel(const int* __restrict__ ei, int* __restrict__ cur,
                                                      int* __restrict__ ssrc, int* __restrict__ seid) {
    int e = blockIdx.x * 256 + threadIdx.x;
    if (e >= N_EDGES) return;
    int d = ei[N_EDGES + e];
    int p = atomicAdd(&cur[d], 1);
    ssrc[p] = ei[e];
    seid[p] = e;
}

// ---------------- edge projection, layer 1: q1[s][96] = relu(ea@W1+b1)@V1 + b1f ----------------
__global__ __launch_bounds__(128) void edgeq1_kernel(
    const float* __restrict__ edge_attr, const int* __restrict__ seid,
    const float* __restrict__ w1, const float* __restrict__ b1,
    const float* __restrict__ fw, unsigned int* __restrict__ q1)
{
    __shared__ float ts[64 * 128];
    const int tid = threadIdx.x;
    const int s = blockIdx.x * 128 + tid;
    const int e = seid[s];

    float t[64];
#pragma unroll
    for (int m = 0; m < 64; m++) t[m] = b1[m];
#pragma unroll
    for (int k4 = 0; k4 < 4; k4++) {
        const float4 a = *(const float4*)(edge_attr + (size_t)e * 16 + k4 * 4);
#pragma unroll
        for (int m = 0; m < 64; m++) t[m] = fmaf(a.x, w1[(k4 * 4 + 0) * 64 + m], t[m]);
#pragma unroll
        for (int m = 0; m < 64; m++) t[m] = fmaf(a.y, w1[(k4 * 4 + 1) * 64 + m], t[m]);
#pragma unroll
        for (int m = 0; m < 64; m++) t[m] = fmaf(a.z, w1[(k4 * 4 + 2) * 64 + m], t[m]);
#pragma unroll
        for (int m = 0; m < 64; m++) t[m] = fmaf(a.w, w1[(k4 * 4 + 3) * 64 + m], t[m]);
    }
#pragma unroll
    for (int m = 0; m < 64; m++) ts[m * 128 + tid] = fmaxf(t[m], 0.f);

    const float* V  = fw + F_V1H;
    const float* bf = fw + F_B1F;
    for (int i = 0; i < 3; i++) {
        float p[32];
#pragma unroll
        for (int j = 0; j < 32; j++) p[j] = bf[i * 32 + j];
        for (int k = 0; k < 64; k++) {
            float tk = ts[k * 128 + tid];
#pragma unroll
            for (int j = 0; j < 32; j++) p[j] = fmaf(tk, V[k * 96 + i * 32 + j], p[j]);
        }
        uint4* dst = (uint4*)(q1 + (size_t)s * 48 + i * 16);
#pragma unroll
        for (int j4 = 0; j4 < 4; j4++) {
            dst[j4] = make_uint4(pack2bf(p[j4 * 8 + 0], p[j4 * 8 + 1]),
                                 pack2bf(p[j4 * 8 + 2], p[j4 * 8 + 3]),
                                 pack2bf(p[j4 * 8 + 4], p[j4 * 8 + 5]),
                                 pack2bf(p[j4 * 8 + 6], p[j4 * 8 + 7]));
        }
    }
}

// ---------------- gather + node MLP, layer 1 (one node per 64-thread block) ----------------
__global__ __launch_bounds__(64) void gather_node1_kernel(
    const float* __restrict__ x, const int* __restrict__ off, const int* __restrict__ ssrc,
    const unsigned int* __restrict__ q1,
    const float* __restrict__ c1_w1, const float* __restrict__ c1_b1,
    const float* __restrict__ fw, float* __restrict__ h1)
{
    __shared__ float agg[96];
    __shared__ float inb[96];
    __shared__ float zl[64];
    const int n = blockIdx.x, l = threadIdx.x;
    const int s0 = off[n], s1 = off[n + 1];

    if (l < 48) {
        float a0 = 0.f, a1 = 0.f;
        const int j = (2 * l) & 31;
        for (int s = s0; s < s1; s++) {
            const int src = ssrc[s];
            const unsigned int u = q1[(size_t)s * 48 + l];
            const float2 xv = *(const float2*)(x + (size_t)src * 32 + j);
            a0 += fmaxf(xv.x + bflo(u), 0.f);
            a1 += fmaxf(xv.y + bfhi(u), 0.f);
        }
        agg[2 * l] = a0; agg[2 * l + 1] = a1;
    }
    __syncthreads();
    inb[l] = x[(size_t)n * 32 + (l & 31)] + agg[l];
    if (l < 32) inb[64 + l] = x[(size_t)n * 32 + l] + agg[64 + l];
    __syncthreads();

    const float* U1  = fw + F_U1;
    float acc = fw[F_UB1 + l];
    for (int i = 0; i < 3; i++) {
        float z = c1_b1[i * 64 + l];
#pragma unroll
        for (int k = 0; k < 32; k++) z = fmaf(inb[i * 32 + k], c1_w1[i * 2048 + k * 64 + l], z);
        zl[l] = fmaxf(z, 0.f);
        __syncthreads();
#pragma unroll
        for (int k = 0; k < 64; k++) acc = fmaf(zl[k], U1[i * 4096 + k * 64 + l], acc);
        __syncthreads();
    }
    h1[(size_t)n * 64 + l] = fmaxf(acc, 0.f);
}

// ---------------- edge projection, layer 2 (chunked): q2[s-lo][192] ----------------
__global__ __launch_bounds__(128) void edgeq2_kernel(
    const float* __restrict__ edge_attr, const int* __restrict__ seid,
    const float* __restrict__ w1, const float* __restrict__ b1,
    const float* __restrict__ fw, unsigned int* __restrict__ q2, int lo)
{
    __shared__ float ts[64 * 128];
    const int tid = threadIdx.x;
    const int s = lo + blockIdx.x * 128 + tid;
    const int e = seid[s];

    float t[64];
#pragma unroll
    for (int m = 0; m < 64; m++) t[m] = b1[m];
#pragma unroll
    for (int k4 = 0; k4 < 4; k4++) {
        const float4 a = *(const float4*)(edge_attr + (size_t)e * 16 + k4 * 4);
#pragma unroll
        for (int m = 0; m < 64; m++) t[m] = fmaf(a.x, w1[(k4 * 4 + 0) * 64 + m], t[m]);
#pragma unroll
        for (int m = 0; m < 64; m++) t[m] = fmaf(a.y, w1[(k4 * 4 + 1) * 64 + m], t[m]);
#pragma unroll
        for (int m = 0; m < 64; m++) t[m] = fmaf(a.z, w1[(k4 * 4 + 2) * 64 + m], t[m]);
#pragma unroll
        for (int m = 0; m < 64; m++) t[m] = fmaf(a.w, w1[(k4 * 4 + 3) * 64 + m], t[m]);
    }
#pragma unroll
    for (int m = 0; m < 64; m++) ts[m * 128 + tid] = fmaxf(t[m], 0.f);

    const float* V  = fw + F_V2H;
    const float* bf = fw + F_B2F;
    for (int i = 0; i < 3; i++) {
        float p[64];
#pragma unroll
        for (int j = 0; j < 64; j++) p[j] = bf[i * 64 + j];
        for (int k = 0; k < 64; k++) {
            float tk = ts[k * 128 + tid];
#pragma unroll
            for (int j = 0; j < 64; j++) p[j] = fmaf(tk, V[k * 192 + i * 64 + j], p[j]);
        }
        uint4* dst = (uint4*)(q2 + (size_t)(s - lo) * 96 + i * 32);
#pragma unroll
        for (int j4 = 0; j4 < 8; j4++) {
            dst[j4] = make_uint4(pack2bf(p[j4 * 8 + 0], p[j4 * 8 + 1]),
                                 pack2bf(p[j4 * 8 + 2], p[j4 * 8 + 3]),
                                 pack2bf(p[j4 * 8 + 4], p[j4 * 8 + 5]),
                                 pack2bf(p[j4 * 8 + 6], p[j4 * 8 + 7]));
        }
    }
}

// ---------------- gather layer 2 (chunked, accumulates into agg2) ----------------
__global__ __launch_bounds__(64) void gather2_kernel(
    const float* __restrict__ h1, const int* __restrict__ off, const int* __restrict__ ssrc,
    const unsigned int* __restrict__ q2, float* __restrict__ agg2, int lo, int hi)
{
    const int n = blockIdx.x, l = threadIdx.x;
    int s0 = off[n], s1 = off[n + 1];
    if (s0 < lo) s0 = lo;
    if (s1 > hi) s1 = hi;
    if (s0 >= s1) return;

    float a0 = 0.f, a1 = 0.f, b0 = 0.f, b1 = 0.f;
    const int j = (2 * l) & 63;
    for (int s = s0; s < s1; s++) {
        const int src = ssrc[s];
        const float2 hv = *(const float2*)(h1 + (size_t)src * 64 + j);
        const unsigned int u = q2[(size_t)(s - lo) * 96 + l];
        a0 += fmaxf(hv.x + bflo(u), 0.f);
        a1 += fmaxf(hv.y + bfhi(u), 0.f);
        if (l < 32) {
            const unsigned int u2 = q2[(size_t)(s - lo) * 96 + 64 + l];
            b0 += fmaxf(hv.x + bflo(u2), 0.f);
            b1 += fmaxf(hv.y + bfhi(u2), 0.f);
        }
    }
    float2* ap = (float2*)(agg2 + (size_t)n * 192 + 2 * l);
    float2 av = *ap; av.x += a0; av.y += a1; *ap = av;
    if (l < 32) {
        float2* bp = (float2*)(agg2 + (size_t)n * 192 + 128 + 2 * l);
        float2 bv = *bp; bv.x += b0; bv.y += b1; *bp = bv;
    }
}

// ---------------- node MLP layer 2 ----------------
__global__ __launch_bounds__(64) void node2_kernel(
    const float* __restrict__ h1, const float* __restrict__ agg2,
    const float* __restrict__ c2_w1, const float* __restrict__ c2_b1,
    const float* __restrict__ fw, float* __restrict__ h2)
{
    __shared__ float inb[192];
    __shared__ float zl[64];
    const int n = blockIdx.x, l = threadIdx.x;
    const float hval = h1[(size_t)n * 64 + l];
    inb[l]       = hval + agg2[(size_t)n * 192 + l];
    inb[64 + l]  = hval + agg2[(size_t)n * 192 + 64 + l];
    inb[128 + l] = hval + agg2[(size_t)n * 192 + 128 + l];
    __syncthreads();

    const float* U2 = fw + F_U2;
    float acc = fw[F_UB2 + l];
    for (int i = 0; i < 3; i++) {
        float z = c2_b1[i * 64 + l];
#pragma unroll
        for (int k = 0; k < 64; k++) z = fmaf(inb[i * 64 + k], c2_w1[i * 4096 + k * 64 + l], z);
        zl[l] = fmaxf(z, 0.f);
        __syncthreads();
#pragma unroll
        for (int k = 0; k < 64; k++) acc = fmaf(zl[k], U2[i * 4096 + k * 64 + l], acc);
        __syncthreads();
    }
    h2[(size_t)n * 64 + l] = fmaxf(acc, 0.f);
}

// ---------------- pooling (batch is sorted: binary-search graph bounds) ----------------
__global__ __launch_bounds__(256) void pool_kernel(
    const float* __restrict__ h2, const int* __restrict__ batch,
    float* __restrict__ gsum, float* __restrict__ gcnt)
{
    __shared__ float red[256];
    const int g = blockIdx.x, t = threadIdx.x;
    int lo = 0, hi = N_NODES;
    while (lo < hi) { int m = (lo + hi) >> 1; if (batch[m] < g) lo = m + 1; else hi = m; }
    int lo2 = lo, hi2 = N_NODES;
    while (lo2 < hi2) { int m = (lo2 + hi2) >> 1; if (batch[m] < g + 1) lo2 = m + 1; else hi2 = m; }

    const int col = t & 63, ch = t >> 6;
    float s = 0.f;
    for (int idx = lo + ch; idx < lo2; idx += 4) s += h2[(size_t)idx * 64 + col];
    red[t] = s;
    __syncthreads();
    if (t < 64) gsum[(size_t)g * 64 + t] = red[t] + red[64 + t] + red[128 + t] + red[192 + t];
    if (t == 0) gcnt[g] = (float)(lo2 - lo);
}

// ---------------- final: mean-pool divide + fc ----------------
__global__ __launch_bounds__(256) void final_kernel(
    const float* __restrict__ gsum, const float* __restrict__ gcnt,
    const float* __restrict__ u, const float* __restrict__ fc_w,
    const float* __restrict__ fc_b, float* __restrict__ out)
{
    int g = blockIdx.x * 256 + threadIdx.x;
    if (g >= N_GRAPHS) return;
    float inv = 1.f / fmaxf(gcnt[g], 1.f);
    float s = fc_b[0];
#pragma unroll
    for (int j = 0; j < 64; j++) s = fmaf(gsum[(size_t)g * 64 + j] * inv, fc_w[j], s);
#pragma unroll
    for (int k = 0; k < 32; k++) s = fmaf(u[(size_t)g * 32 + k], fc_w[64 + k], s);
    out[g] = s;
}

extern "C" void kernel_launch(void* const* d_in, const int* in_sizes, int n_in,
                              void* d_out, int out_size, void* d_ws, size_t ws_size,
                              hipStream_t stream) {
    (void)in_sizes; (void)n_in; (void)out_size; (void)ws_size;
    const float* x        = (const float*)d_in[0];
    const float* edge_attr= (const float*)d_in[1];
    const float* u        = (const float*)d_in[2];
    const float* em1_w1   = (const float*)d_in[3];
    const float* em1_b1   = (const float*)d_in[4];
    const float* em1_w2   = (const float*)d_in[5];
    const float* em1_b2   = (const float*)d_in[6];
    const float* em2_w1   = (const float*)d_in[7];
    const float* em2_b1   = (const float*)d_in[8];
    const float* em2_w2   = (const float*)d_in[9];
    const float* em2_b2   = (const float*)d_in[10];
    const float* c1_lin_w = (const float*)d_in[11];
    const float* c1_lin_b = (const float*)d_in[12];
    const float* c1_w1    = (const float*)d_in[13];
    const float* c1_b1    = (const float*)d_in[14];
    const float* c1_w2    = (const float*)d_in[15];
    const float* c1_b2    = (const float*)d_in[16];
    const float* c2_lin_w = (const float*)d_in[17];
    const float* c2_lin_b = (const float*)d_in[18];
    const float* c2_w1    = (const float*)d_in[19];
    const float* c2_b1    = (const float*)d_in[20];
    const float* c2_w2    = (const float*)d_in[21];
    const float* c2_b2    = (const float*)d_in[22];
    const float* lin1_w   = (const float*)d_in[23];
    const float* lin1_b   = (const float*)d_in[24];
    const float* lin2_w   = (const float*)d_in[25];
    const float* lin2_b   = (const float*)d_in[26];
    const float* fc_w     = (const float*)d_in[27];
    const float* fc_b     = (const float*)d_in[28];
    const int*   ei       = (const int*)d_in[29];
    const int*   batch    = (const int*)d_in[30];

    char* wsb = (char*)d_ws;
    int*   cnt  = (int*)(wsb + B_CNT);
    float* gsum = (float*)(wsb + B_GSUM);
    float* gcnt = (float*)(wsb + B_GCNT);
    float* agg2 = (float*)(wsb + B_AGG2);
    int*   off  = (int*)(wsb + B_OFF);
    int*   cur  = (int*)(wsb + B_CUR);
    int*   bsum = (int*)(wsb + B_BSUM);
    int*   ssrc = (int*)(wsb + B_SSRC);
    int*   seid = (int*)(wsb + B_SEID);
    unsigned int* q = (unsigned int*)(wsb + B_Q);
    float* h1   = (float*)(wsb + B_H1);
    float* h2   = (float*)(wsb + B_H2);
    float* fw   = (float*)(wsb + B_FOLD);
    float* out  = (float*)d_out;

    hipMemsetAsync(d_ws, 0, ZERO_BYTES, stream);

    fold_kernel<<<(FOLD_TOTAL + 255) / 256, 256, 0, stream>>>(
        em1_w2, em1_b2, em2_w2, em2_b2, c1_lin_w, c1_lin_b, c2_lin_w, c2_lin_b,
        c1_w2, c1_b2, c2_w2, c2_b2, lin1_w, lin1_b, lin2_w, lin2_b, fw);

    // counting sort by dst
    hist_kernel<<<N_EDGES / 256, 256, 0, stream>>>(ei, cnt);
    scan1_kernel<<<196, 256, 0, stream>>>(cnt, off, bsum);
    scan2_kernel<<<1, 256, 0, stream>>>(bsum);
    scan3_kernel<<<196, 256, 0, stream>>>(off, bsum, cur);
    scatter_kernel<<<N_EDGES / 256, 256, 0, stream>>>(ei, cur, ssrc, seid);

    // layer 1
    edgeq1_kernel<<<N_EDGES / 128, 128, 0, stream>>>(edge_attr, seid, em1_w1, em1_b1, fw, q);
    gather_node1_kernel<<<N_NODES, 64, 0, stream>>>(x, off, ssrc, q, c1_w1, c1_b1, fw, h1);

    // layer 2 (two chunks, q buffer reused)
    for (int c = 0; c < 2; c++) {
        const int lo = c * ECHUNK, hi = lo + ECHUNK;
        edgeq2_kernel<<<ECHUNK / 128, 128, 0, stream>>>(edge_attr, seid, em2_w1, em2_b1, fw, q, lo);
        gather2_kernel<<<N_NODES, 64, 0, stream>>>(h1, off, ssrc, q, agg2, lo, hi);
    }
    node2_kernel<<<N_NODES, 64, 0, stream>>>(h1, agg2, c2_w1, c2_b1, fw, h2);

    // pooling + head
    pool_kernel<<<N_GRAPHS, 256, 0, stream>>>(h2, batch, gsum, gcnt);
    final_kernel<<<(N_GRAPHS + 255) / 256, 256, 0, stream>>>(gsum, gcnt, u, fc_w, fc_b, out);
}

// Round 3
// 1724.575 us; speedup vs baseline: 7.3535x; 1.0007x over previous
//
#include <hip/hip_runtime.h>
#include <hip/hip_bf16.h>

#define N_NODES  50000
#define N_EDGES  800000
#define N_GRAPHS 512
#define ECHUNK   400000

// ---------------- workspace layout (BYTE offsets, 256-aligned) ----------------
constexpr size_t B_CNT  = 0;                 // N ints (zeroed)
constexpr size_t ZERO_BYTES = 200192;
constexpr size_t B_OFF  = 200192;            // (N+1) ints
constexpr size_t B_CUR  = 400384;            // N ints
constexpr size_t B_BSUM = 600576;            // 256 ints
constexpr size_t B_SSRC = 601600;            // E ints  (src of sorted edge)
constexpr size_t B_SEID = 3801600;           // E ints  (orig edge id of sorted edge)
constexpr size_t B_GSUM = 7001600;           // 512*64 f
constexpr size_t B_GCNT = 7132672;           // 512 f
constexpr size_t B_AGG2 = 7134720;           // N*192 f (chunk0 writes, chunk1 accumulates)
constexpr size_t B_Q    = 45534720;          // 153.6 MB bf16 (q1[E][96] | q2[ECHUNK][192])
constexpr size_t B_H1   = 199134720;         // N*64 f
constexpr size_t B_H2   = 211934720;         // N*64 f
constexpr size_t B_FOLD = 224734720;         // folded weights, 43424 floats
// fold-region float offsets
constexpr int F_V1H = 0;      // [64][96]
constexpr int F_B1F = 6144;   // [96]
constexpr int F_V2H = 6240;   // [64][192]
constexpr int F_B2F = 18528;  // [192]
constexpr int F_U1  = 18720;  // [3][64][64]
constexpr int F_UB1 = 31008;  // [64]
constexpr int F_U2  = 31072;  // [3][64][64]
constexpr int F_UB2 = 43360;  // [64]
constexpr int FOLD_TOTAL = 43424;

__device__ inline unsigned int pack2bf(float a, float b) {
    unsigned int ua = __float_as_uint(a), ub = __float_as_uint(b);
    return ((ua + 0x7FFFu + ((ua >> 16) & 1u)) >> 16) |
           ((ub + 0x7FFFu + ((ub >> 16) & 1u)) & 0xFFFF0000u);
}
__device__ inline float bflo(unsigned int u) { return __uint_as_float(u << 16); }
__device__ inline float bfhi(unsigned int u) { return __uint_as_float(u & 0xFFFF0000u); }

// ---------------- fold: precompute folded weight products ----------------
__global__ __launch_bounds__(256) void fold_kernel(
    const float* __restrict__ em1_w2, const float* __restrict__ em1_b2,
    const float* __restrict__ em2_w2, const float* __restrict__ em2_b2,
    const float* __restrict__ c1_lin_w, const float* __restrict__ c1_lin_b,
    const float* __restrict__ c2_lin_w, const float* __restrict__ c2_lin_b,
    const float* __restrict__ c1_w2, const float* __restrict__ c1_b2,
    const float* __restrict__ c2_w2, const float* __restrict__ c2_b2,
    const float* __restrict__ lin1_w, const float* __restrict__ lin1_b,
    const float* __restrict__ lin2_w, const float* __restrict__ lin2_b,
    float* __restrict__ fw)
{
    int idx = blockIdx.x * 256 + threadIdx.x;
    if (idx >= FOLD_TOTAL) return;
    int r = idx;
    if (r < 6144) {                        // V1H[k][i*32+j] = sum_m em1_w2[k][m]*c1_lin_w[i][m][j]
        int k = r / 96, c = r % 96, i = c / 32, j = c % 32;
        float s = 0.f;
        for (int m = 0; m < 64; m++) s = fmaf(em1_w2[k * 64 + m], c1_lin_w[i * 2048 + m * 32 + j], s);
        fw[F_V1H + r] = s; return;
    }
    r -= 6144;
    if (r < 96) {                          // B1F = em1_b2 @ c1_lin_w + c1_lin_b
        int i = r / 32, j = r % 32;
        float s = c1_lin_b[r];
        for (int m = 0; m < 64; m++) s = fmaf(em1_b2[m], c1_lin_w[i * 2048 + m * 32 + j], s);
        fw[F_B1F + r] = s; return;
    }
    r -= 96;
    if (r < 12288) {                       // V2H[k][i*64+j]
        int k = r / 192, c = r % 192, i = c / 64, j = c % 64;
        float s = 0.f;
        for (int m = 0; m < 64; m++) s = fmaf(em2_w2[k * 64 + m], c2_lin_w[i * 4096 + m * 64 + j], s);
        fw[F_V2H + r] = s; return;
    }
    r -= 12288;
    if (r < 192) {
        int i = r / 64, j = r % 64;
        float s = c2_lin_b[r];
        for (int m = 0; m < 64; m++) s = fmaf(em2_b2[m], c2_lin_w[i * 4096 + m * 64 + j], s);
        fw[F_B2F + r] = s; return;
    }
    r -= 192;
    if (r < 12288) {                       // U1[i][k][j] = sum_m c1_w2[i][k][m]*lin1_w[(i*64+m)][j]
        int i = r / 4096, k = (r / 64) % 64, j = r % 64;
        float s = 0.f;
        for (int m = 0; m < 64; m++) s = fmaf(c1_w2[i * 4096 + k * 64 + m], lin1_w[(i * 64 + m) * 64 + j], s);
        fw[F_U1 + r] = s; return;
    }
    r -= 12288;
    if (r < 64) {                          // UB1
        float s = lin1_b[r];
        for (int i = 0; i < 3; i++)
            for (int m = 0; m < 64; m++) s = fmaf(c1_b2[i * 64 + m], lin1_w[(i * 64 + m) * 64 + r], s);
        fw[F_UB1 + r] = s; return;
    }
    r -= 64;
    if (r < 12288) {                       // U2
        int i = r / 4096, k = (r / 64) % 64, j = r % 64;
        float s = 0.f;
        for (int m = 0; m < 64; m++) s = fmaf(c2_w2[i * 4096 + k * 64 + m], lin2_w[(i * 64 + m) * 64 + j], s);
        fw[F_U2 + r] = s; return;
    }
    r -= 12288;
    {                                      // UB2
        float s = lin2_b[r];
        for (int i = 0; i < 3; i++)
            for (int m = 0; m < 64; m++) s = fmaf(c2_b2[i * 64 + m], lin2_w[(i * 64 + m) * 64 + r], s);
        fw[F_UB2 + r] = s; return;
    }
}

// ---------------- counting sort: hist -> scan -> scatter ----------------
__global__ __launch_bounds__(256) void hist_kernel(const int* __restrict__ ei, int* __restrict__ cnt) {
    int e = blockIdx.x * 256 + threadIdx.x;
    if (e < N_EDGES) atomicAdd(&cnt[ei[N_EDGES + e]], 1);
}

__global__ __launch_bounds__(256) void scan1_kernel(const int* __restrict__ cnt,
                                                    int* __restrict__ off, int* __restrict__ bsum) {
    __shared__ int sh[256];
    int t = threadIdx.x, i = blockIdx.x * 256 + t;
    int v = (i < N_NODES) ? cnt[i] : 0;
    sh[t] = v; __syncthreads();
    for (int d = 1; d < 256; d <<= 1) {
        int add = (t >= d) ? sh[t - d] : 0;
        __syncthreads();
        sh[t] += add;
        __syncthreads();
    }
    if (i < N_NODES) off[i] = sh[t] - v;     // exclusive
    if (t == 255) bsum[blockIdx.x] = sh[255];
}

__global__ __launch_bounds__(256) void scan2_kernel(int* __restrict__ bsum) {
    __shared__ int sh[256];
    int t = threadIdx.x;
    int v = (t < 196) ? bsum[t] : 0;
    sh[t] = v; __syncthreads();
    for (int d = 1; d < 256; d <<= 1) {
        int add = (t >= d) ? sh[t - d] : 0;
        __syncthreads();
        sh[t] += add;
        __syncthreads();
    }
    bsum[t] = sh[t] - v;                      // exclusive
}

__global__ __launch_bounds__(256) void scan3_kernel(int* __restrict__ off, const int* __restrict__ bsum,
                                                    int* __restrict__ cur) {
    int i = blockIdx.x * 256 + threadIdx.x;
    if (i < N_NODES) {
        int o = off[i] + bsum[i >> 8];
        off[i] = o;
        cur[i] = o;
    }
    if (i == 0) off[N_NODES] = N_EDGES;
}

__global__ __launch_bounds__(256) void scatter_kernel(const int* __restrict__ ei, int* __restrict__ cur,
                                                      int* __restrict__ ssrc, int* __restrict__ seid) {
    int e = blockIdx.x * 256 + threadIdx.x;
    if (e >= N_EDGES) return;
    int d = ei[N_EDGES + e];
    int p = atomicAdd(&cur[d], 1);
    ssrc[p] = ei[e];
    seid[p] = e;
}

// ---------------- edge projection, layer 1 ----------------
// q1[s][96] = (relu(ea@W1+b1) @ V1 + b1f) as bf16.  t[64] lives in VGPRs;
// k-loop fully unrolled (static indices), j chunked to 16 to bound code size.
// V/W accesses are wave-uniform -> scalar pipe; no LDS at all.
__global__ __launch_bounds__(256) void edgeq1_kernel(
    const float* __restrict__ edge_attr, const int* __restrict__ seid,
    const float* __restrict__ w1, const float* __restrict__ b1,
    const float* __restrict__ fw, unsigned int* __restrict__ q1)
{
    const int s = blockIdx.x * 256 + threadIdx.x;
    const int e = seid[s];

    float t[64];
#pragma unroll
    for (int m = 0; m < 64; m++) t[m] = b1[m];
#pragma unroll
    for (int k4 = 0; k4 < 4; k4++) {
        const float4 a = *(const float4*)(edge_attr + (size_t)e * 16 + k4 * 4);
#pragma unroll
        for (int m = 0; m < 64; m++) t[m] = fmaf(a.x, w1[(k4 * 4 + 0) * 64 + m], t[m]);
#pragma unroll
        for (int m = 0; m < 64; m++) t[m] = fmaf(a.y, w1[(k4 * 4 + 1) * 64 + m], t[m]);
#pragma unroll
        for (int m = 0; m < 64; m++) t[m] = fmaf(a.z, w1[(k4 * 4 + 2) * 64 + m], t[m]);
#pragma unroll
        for (int m = 0; m < 64; m++) t[m] = fmaf(a.w, w1[(k4 * 4 + 3) * 64 + m], t[m]);
    }
#pragma unroll
    for (int m = 0; m < 64; m++) t[m] = fmaxf(t[m], 0.f);

    for (int i = 0; i < 3; i++) {
        for (int jc = 0; jc < 2; jc++) {
            const float* V  = fw + F_V1H + i * 32 + jc * 16;
            const float* bf = fw + F_B1F + i * 32 + jc * 16;
            float p[16];
#pragma unroll
            for (int j = 0; j < 16; j++) p[j] = bf[j];
#pragma unroll
            for (int k = 0; k < 64; k++) {
#pragma unroll
                for (int j = 0; j < 16; j++) p[j] = fmaf(t[k], V[k * 96 + j], p[j]);
            }
            uint4* dst = (uint4*)(q1 + (size_t)s * 48 + i * 16 + jc * 8);
            dst[0] = make_uint4(pack2bf(p[0], p[1]),  pack2bf(p[2], p[3]),
                                pack2bf(p[4], p[5]),  pack2bf(p[6], p[7]));
            dst[1] = make_uint4(pack2bf(p[8], p[9]),  pack2bf(p[10], p[11]),
                                pack2bf(p[12], p[13]),pack2bf(p[14], p[15]));
        }
    }
}

// ---------------- gather + node MLP, layer 1 (one node per 64-thread block) ----------------
__global__ __launch_bounds__(64) void gather_node1_kernel(
    const float* __restrict__ x, const int* __restrict__ off, const int* __restrict__ ssrc,
    const unsigned int* __restrict__ q1,
    const float* __restrict__ c1_w1, const float* __restrict__ c1_b1,
    const float* __restrict__ fw, float* __restrict__ h1)
{
    __shared__ float agg[96];
    __shared__ float inb[96];
    __shared__ float zl[64];
    const int n = blockIdx.x, l = threadIdx.x;
    const int s0 = off[n], s1 = off[n + 1];

    if (l < 48) {
        float a0 = 0.f, a1 = 0.f;
        const int j = (2 * l) & 31;
        for (int s = s0; s < s1; s++) {
            const int src = ssrc[s];
            const unsigned int u = q1[(size_t)s * 48 + l];
            const float2 xv = *(const float2*)(x + (size_t)src * 32 + j);
            a0 += fmaxf(xv.x + bflo(u), 0.f);
            a1 += fmaxf(xv.y + bfhi(u), 0.f);
        }
        agg[2 * l] = a0; agg[2 * l + 1] = a1;
    }
    __syncthreads();
    inb[l] = x[(size_t)n * 32 + (l & 31)] + agg[l];
    if (l < 32) inb[64 + l] = x[(size_t)n * 32 + l] + agg[64 + l];
    __syncthreads();

    const float* U1  = fw + F_U1;
    float acc = fw[F_UB1 + l];
    for (int i = 0; i < 3; i++) {
        float z = c1_b1[i * 64 + l];
#pragma unroll
        for (int k = 0; k < 32; k++) z = fmaf(inb[i * 32 + k], c1_w1[i * 2048 + k * 64 + l], z);
        zl[l] = fmaxf(z, 0.f);
        __syncthreads();
#pragma unroll
        for (int k = 0; k < 64; k++) acc = fmaf(zl[k], U1[i * 4096 + k * 64 + l], acc);
        __syncthreads();
    }
    h1[(size_t)n * 64 + l] = fmaxf(acc, 0.f);
}

// ---------------- edge projection, layer 2 (chunked) ----------------
__global__ __launch_bounds__(256) void edgeq2_kernel(
    const float* __restrict__ edge_attr, const int* __restrict__ seid,
    const float* __restrict__ w1, const float* __restrict__ b1,
    const float* __restrict__ fw, unsigned int* __restrict__ q2, int lo)
{
    const int si = blockIdx.x * 256 + threadIdx.x;
    if (si >= ECHUNK) return;
    const int s = lo + si;
    const int e = seid[s];

    float t[64];
#pragma unroll
    for (int m = 0; m < 64; m++) t[m] = b1[m];
#pragma unroll
    for (int k4 = 0; k4 < 4; k4++) {
        const float4 a = *(const float4*)(edge_attr + (size_t)e * 16 + k4 * 4);
#pragma unroll
        for (int m = 0; m < 64; m++) t[m] = fmaf(a.x, w1[(k4 * 4 + 0) * 64 + m], t[m]);
#pragma unroll
        for (int m = 0; m < 64; m++) t[m] = fmaf(a.y, w1[(k4 * 4 + 1) * 64 + m], t[m]);
#pragma unroll
        for (int m = 0; m < 64; m++) t[m] = fmaf(a.z, w1[(k4 * 4 + 2) * 64 + m], t[m]);
#pragma unroll
        for (int m = 0; m < 64; m++) t[m] = fmaf(a.w, w1[(k4 * 4 + 3) * 64 + m], t[m]);
    }
#pragma unroll
    for (int m = 0; m < 64; m++) t[m] = fmaxf(t[m], 0.f);

    for (int i = 0; i < 3; i++) {
        for (int jc = 0; jc < 4; jc++) {
            const float* V  = fw + F_V2H + i * 64 + jc * 16;
            const float* bf = fw + F_B2F + i * 64 + jc * 16;
            float p[16];
#pragma unroll
            for (int j = 0; j < 16; j++) p[j] = bf[j];
#pragma unroll
            for (int k = 0; k < 64; k++) {
#pragma unroll
                for (int j = 0; j < 16; j++) p[j] = fmaf(t[k], V[k * 192 + j], p[j]);
            }
            uint4* dst = (uint4*)(q2 + (size_t)si * 96 + i * 32 + jc * 8);
            dst[0] = make_uint4(pack2bf(p[0], p[1]),  pack2bf(p[2], p[3]),
                                pack2bf(p[4], p[5]),  pack2bf(p[6], p[7]));
            dst[1] = make_uint4(pack2bf(p[8], p[9]),  pack2bf(p[10], p[11]),
                                pack2bf(p[12], p[13]),pack2bf(p[14], p[15]));
        }
    }
}

// ---------------- gather layer 2 (chunked; chunk0 writes, chunk1 accumulates) ----------------
__global__ __launch_bounds__(64) void gather2_kernel(
    const float* __restrict__ h1, const int* __restrict__ off, const int* __restrict__ ssrc,
    const unsigned int* __restrict__ q2, float* __restrict__ agg2, int lo, int hi, int first)
{
    const int n = blockIdx.x, l = threadIdx.x;
    int s0 = off[n], s1 = off[n + 1];
    if (s0 < lo) s0 = lo;
    if (s1 > hi) s1 = hi;
    if (!first && s0 >= s1) return;

    float a0 = 0.f, a1 = 0.f, b0 = 0.f, b1 = 0.f;
    const int j = (2 * l) & 63;
    for (int s = s0; s < s1; s++) {
        const int src = ssrc[s];
        const float2 hv = *(const float2*)(h1 + (size_t)src * 64 + j);
        const unsigned int u = q2[(size_t)(s - lo) * 96 + l];
        a0 += fmaxf(hv.x + bflo(u), 0.f);
        a1 += fmaxf(hv.y + bfhi(u), 0.f);
        if (l < 32) {
            const unsigned int u2 = q2[(size_t)(s - lo) * 96 + 64 + l];
            b0 += fmaxf(hv.x + bflo(u2), 0.f);
            b1 += fmaxf(hv.y + bfhi(u2), 0.f);
        }
    }
    float2* ap = (float2*)(agg2 + (size_t)n * 192 + 2 * l);
    float2* bp = (float2*)(agg2 + (size_t)n * 192 + 128 + 2 * l);
    if (first) {
        *ap = make_float2(a0, a1);
        if (l < 32) *bp = make_float2(b0, b1);
    } else {
        float2 av = *ap; av.x += a0; av.y += a1; *ap = av;
        if (l < 32) { float2 bv = *bp; bv.x += b0; bv.y += b1; *bp = bv; }
    }
}

// ---------------- node MLP layer 2 ----------------
__global__ __launch_bounds__(64) void node2_kernel(
    const float* __restrict__ h1, const float* __restrict__ agg2,
    const float* __restrict__ c2_w1, const float* __restrict__ c2_b1,
    const float* __restrict__ fw, float* __restrict__ h2)
{
    __shared__ float inb[192];
    __shared__ float zl[64];
    const int n = blockIdx.x, l = threadIdx.x;
    const float hval = h1[(size_t)n * 64 + l];
    inb[l]       = hval + agg2[(size_t)n * 192 + l];
    inb[64 + l]  = hval + agg2[(size_t)n * 192 + 64 + l];
    inb[128 + l] = hval + agg2[(size_t)n * 192 + 128 + l];
    __syncthreads();

    const float* U2 = fw + F_U2;
    float acc = fw[F_UB2 + l];
    for (int i = 0; i < 3; i++) {
        float z = c2_b1[i * 64 + l];
#pragma unroll
        for (int k = 0; k < 64; k++) z = fmaf(inb[i * 64 + k], c2_w1[i * 4096 + k * 64 + l], z);
        zl[l] = fmaxf(z, 0.f);
        __syncthreads();
#pragma unroll
        for (int k = 0; k < 64; k++) acc = fmaf(zl[k], U2[i * 4096 + k * 64 + l], acc);
        __syncthreads();
    }
    h2[(size_t)n * 64 + l] = fmaxf(acc, 0.f);
}

// ---------------- pooling (batch is sorted: binary-search graph bounds) ----------------
__global__ __launch_bounds__(256) void pool_kernel(
    const float* __restrict__ h2, const int* __restrict__ batch,
    float* __restrict__ gsum, float* __restrict__ gcnt)
{
    __shared__ float red[256];
    const int g = blockIdx.x, t = threadIdx.x;
    int lo = 0, hi = N_NODES;
    while (lo < hi) { int m = (lo + hi) >> 1; if (batch[m] < g) lo = m + 1; else hi = m; }
    int lo2 = lo, hi2 = N_NODES;
    while (lo2 < hi2) { int m = (lo2 + hi2) >> 1; if (batch[m] < g + 1) lo2 = m + 1; else hi2 = m; }

    const int col = t & 63, ch = t >> 6;
    float s = 0.f;
    for (int idx = lo + ch; idx < lo2; idx += 4) s += h2[(size_t)idx * 64 + col];
    red[t] = s;
    __syncthreads();
    if (t < 64) gsum[(size_t)g * 64 + t] = red[t] + red[64 + t] + red[128 + t] + red[192 + t];
    if (t == 0) gcnt[g] = (float)(lo2 - lo);
}

// ---------------- final: mean-pool divide + fc ----------------
__global__ __launch_bounds__(256) void final_kernel(
    const float* __restrict__ gsum, const float* __restrict__ gcnt,
    const float* __restrict__ u, const float* __restrict__ fc_w,
    const float* __restrict__ fc_b, float* __restrict__ out)
{
    int g = blockIdx.x * 256 + threadIdx.x;
    if (g >= N_GRAPHS) return;
    float inv = 1.f / fmaxf(gcnt[g], 1.f);
    float s = fc_b[0];
#pragma unroll
    for (int j = 0; j < 64; j++) s = fmaf(gsum[(size_t)g * 64 + j] * inv, fc_w[j], s);
#pragma unroll
    for (int k = 0; k < 32; k++) s = fmaf(u[(size_t)g * 32 + k], fc_w[64 + k], s);
    out[g] = s;
}

extern "C" void kernel_launch(void* const* d_in, const int* in_sizes, int n_in,
                              void* d_out, int out_size, void* d_ws, size_t ws_size,
                              hipStream_t stream) {
    (void)in_sizes; (void)n_in; (void)out_size; (void)ws_size;
    const float* x        = (const float*)d_in[0];
    const float* edge_attr= (const float*)d_in[1];
    const float* u        = (const float*)d_in[2];
    const float* em1_w1   = (const float*)d_in[3];
    const float* em1_b1   = (const float*)d_in[4];
    const float* em1_w2   = (const float*)d_in[5];
    const float* em1_b2   = (const float*)d_in[6];
    const float* em2_w1   = (const float*)d_in[7];
    const float* em2_b1   = (const float*)d_in[8];
    const float* em2_w2   = (const float*)d_in[9];
    const float* em2_b2   = (const float*)d_in[10];
    const float* c1_lin_w = (const float*)d_in[11];
    const float* c1_lin_b = (const float*)d_in[12];
    const float* c1_w1    = (const float*)d_in[13];
    const float* c1_b1    = (const float*)d_in[14];
    const float* c1_w2    = (const float*)d_in[15];
    const float* c1_b2    = (const float*)d_in[16];
    const float* c2_lin_w = (const float*)d_in[17];
    const float* c2_lin_b = (const float*)d_in[18];
    const float* c2_w1    = (const float*)d_in[19];
    const float* c2_b1    = (const float*)d_in[20];
    const float* c2_w2    = (const float*)d_in[21];
    const float* c2_b2    = (const float*)d_in[22];
    const float* lin1_w   = (const float*)d_in[23];
    const float* lin1_b   = (const float*)d_in[24];
    const float* lin2_w   = (const float*)d_in[25];
    const float* lin2_b   = (const float*)d_in[26];
    const float* fc_w     = (const float*)d_in[27];
    const float* fc_b     = (const float*)d_in[28];
    const int*   ei       = (const int*)d_in[29];
    const int*   batch    = (const int*)d_in[30];

    char* wsb = (char*)d_ws;
    int*   cnt  = (int*)(wsb + B_CNT);
    int*   off  = (int*)(wsb + B_OFF);
    int*   cur  = (int*)(wsb + B_CUR);
    int*   bsum = (int*)(wsb + B_BSUM);
    int*   ssrc = (int*)(wsb + B_SSRC);
    int*   seid = (int*)(wsb + B_SEID);
    float* gsum = (float*)(wsb + B_GSUM);
    float* gcnt = (float*)(wsb + B_GCNT);
    float* agg2 = (float*)(wsb + B_AGG2);
    unsigned int* q = (unsigned int*)(wsb + B_Q);
    float* h1   = (float*)(wsb + B_H1);
    float* h2   = (float*)(wsb + B_H2);
    float* fw   = (float*)(wsb + B_FOLD);
    float* out  = (float*)d_out;

    hipMemsetAsync(d_ws, 0, ZERO_BYTES, stream);   // histogram counters only

    fold_kernel<<<(FOLD_TOTAL + 255) / 256, 256, 0, stream>>>(
        em1_w2, em1_b2, em2_w2, em2_b2, c1_lin_w, c1_lin_b, c2_lin_w, c2_lin_b,
        c1_w2, c1_b2, c2_w2, c2_b2, lin1_w, lin1_b, lin2_w, lin2_b, fw);

    // counting sort by dst
    hist_kernel<<<N_EDGES / 256, 256, 0, stream>>>(ei, cnt);
    scan1_kernel<<<196, 256, 0, stream>>>(cnt, off, bsum);
    scan2_kernel<<<1, 256, 0, stream>>>(bsum);
    scan3_kernel<<<196, 256, 0, stream>>>(off, bsum, cur);
    scatter_kernel<<<N_EDGES / 256, 256, 0, stream>>>(ei, cur, ssrc, seid);

    // layer 1
    edgeq1_kernel<<<N_EDGES / 256, 256, 0, stream>>>(edge_attr, seid, em1_w1, em1_b1, fw, q);
    gather_node1_kernel<<<N_NODES, 64, 0, stream>>>(x, off, ssrc, q, c1_w1, c1_b1, fw, h1);

    // layer 2 (two chunks, q buffer reused)
    for (int c = 0; c < 2; c++) {
        const int lo = c * ECHUNK, hi = lo + ECHUNK;
        edgeq2_kernel<<<(ECHUNK + 255) / 256, 256, 0, stream>>>(edge_attr, seid, em2_w1, em2_b1, fw, q, lo);
        gather2_kernel<<<N_NODES, 64, 0, stream>>>(h1, off, ssrc, q, agg2, lo, hi, c == 0 ? 1 : 0);
    }
    node2_kernel<<<N_NODES, 64, 0, stream>>>(h1, agg2, c2_w1, c2_b1, fw, h2);

    // pooling + head
    pool_kernel<<<N_GRAPHS, 256, 0, stream>>>(h2, batch, gsum, gcnt);
    final_kernel<<<(N_GRAPHS + 255) / 256, 256, 0, stream>>>(gsum, gcnt, u, fc_w, fc_b, out);
}

// Round 5
// 800.717 us; speedup vs baseline: 15.8378x; 2.1538x over previous
//
#include <hip/hip_runtime.h>
#include <hip/hip_bf16.h>

#define N_NODES  50000
#define N_EDGES  800000
#define N_GRAPHS 512
#define ECHUNK   400000

typedef short bf16x8 __attribute__((ext_vector_type(8)));
typedef float f32x4  __attribute__((ext_vector_type(4)));

// ---------------- workspace layout (BYTE offsets, 256-aligned) ----------------
constexpr size_t B_CNT  = 0;                 // N ints (zeroed)
constexpr size_t ZERO_BYTES = 200192;
constexpr size_t B_OFF  = 200192;            // (N+1) ints
constexpr size_t B_CUR  = 400384;            // N ints
constexpr size_t B_BSUM = 600576;            // 256 ints
constexpr size_t B_SSRC = 601600;            // E ints  (src of sorted edge)
constexpr size_t B_SEID = 3801600;           // E ints  (orig edge id of sorted edge)
constexpr size_t B_GSUM = 7001600;           // 512*64 f
constexpr size_t B_GCNT = 7132672;           // 512 f
constexpr size_t B_AGG2 = 7134720;           // N*192 f (permuted col order)
constexpr size_t B_Q    = 45534720;          // 153.6 MB (q1[E][48]u32 | q2[ECHUNK][96]u32)
constexpr size_t B_H1   = 199134720;         // N*64 f
constexpr size_t B_H2   = 211934720;         // N*64 f
constexpr size_t B_FOLD = 224734720;         // folded weights, 43424 floats
constexpr size_t B_FRAG = 224908416;         // bf16 MFMA fragment weights (22528 ushorts)
// fold-region float offsets
constexpr int F_V1H = 0;      // [64][96]   V1[t][n]
constexpr int F_B1F = 6144;   // [96]
constexpr int F_V2H = 6240;   // [64][192]  V2[t][n]
constexpr int F_B2F = 18528;  // [192]
constexpr int F_U1  = 18720;  // [3][64][64]
constexpr int F_UB1 = 31008;  // [64]
constexpr int F_U2  = 31072;  // [3][64][64]
constexpr int F_UB2 = 43360;  // [64]
constexpr int FOLD_TOTAL = 43424;
// frag-region ushort offsets
constexpr int FR_W1E1 = 0;      // [4][64][8]   em1_w1^T A-frags (K padded 16->32)
constexpr int FR_W1E2 = 2048;   // [4][64][8]
constexpr int FR_V1   = 4096;   // [6][2][64][8]  V1 B-frags, k-permuted
constexpr int FR_V2   = 10240;  // [12][2][64][8] V2 B-frags, k-permuted
constexpr int FOLD2_TOTAL = 22528;

__device__ inline float bflo(unsigned int u) { return __uint_as_float(u << 16); }
__device__ inline float bfhi(unsigned int u) { return __uint_as_float(u & 0xFFFF0000u); }
__device__ inline unsigned short bf16u(float x) {
    unsigned int ua = __float_as_uint(x);
    return (unsigned short)((ua + 0x7FFFu + ((ua >> 16) & 1u)) >> 16);
}
__device__ inline unsigned int packbf2(float a, float b) {
    unsigned int ua = __float_as_uint(a), ub = __float_as_uint(b);
    return ((ua + 0x7FFFu + ((ua >> 16) & 1u)) >> 16) |
           ((ub + 0x7FFFu + ((ub >> 16) & 1u)) & 0xFFFF0000u);
}

// ---------------- fold: precompute folded weight products (fp32) ----------------
__global__ __launch_bounds__(256) void fold_kernel(
    const float* __restrict__ em1_w2, const float* __restrict__ em1_b2,
    const float* __restrict__ em2_w2, const float* __restrict__ em2_b2,
    const float* __restrict__ c1_lin_w, const float* __restrict__ c1_lin_b,
    const float* __restrict__ c2_lin_w, const float* __restrict__ c2_lin_b,
    const float* __restrict__ c1_w2, const float* __restrict__ c1_b2,
    const float* __restrict__ c2_w2, const float* __restrict__ c2_b2,
    const float* __restrict__ lin1_w, const float* __restrict__ lin1_b,
    const float* __restrict__ lin2_w, const float* __restrict__ lin2_b,
    float* __restrict__ fw)
{
    int idx = blockIdx.x * 256 + threadIdx.x;
    if (idx >= FOLD_TOTAL) return;
    int r = idx;
    if (r < 6144) {                        // V1H[k][i*32+j] = sum_m em1_w2[k][m]*c1_lin_w[i][m][j]
        int k = r / 96, c = r % 96, i = c / 32, j = c % 32;
        float s = 0.f;
        for (int m = 0; m < 64; m++) s = fmaf(em1_w2[k * 64 + m], c1_lin_w[i * 2048 + m * 32 + j], s);
        fw[F_V1H + r] = s; return;
    }
    r -= 6144;
    if (r < 96) {                          // B1F = em1_b2 @ c1_lin_w + c1_lin_b
        int i = r / 32, j = r % 32;
        float s = c1_lin_b[r];
        for (int m = 0; m < 64; m++) s = fmaf(em1_b2[m], c1_lin_w[i * 2048 + m * 32 + j], s);
        fw[F_B1F + r] = s; return;
    }
    r -= 96;
    if (r < 12288) {                       // V2H[k][i*64+j]
        int k = r / 192, c = r % 192, i = c / 64, j = c % 64;
        float s = 0.f;
        for (int m = 0; m < 64; m++) s = fmaf(em2_w2[k * 64 + m], c2_lin_w[i * 4096 + m * 64 + j], s);
        fw[F_V2H + r] = s; return;
    }
    r -= 12288;
    if (r < 192) {
        int i = r / 64, j = r % 64;
        float s = c2_lin_b[r];
        for (int m = 0; m < 64; m++) s = fmaf(em2_b2[m], c2_lin_w[i * 4096 + m * 64 + j], s);
        fw[F_B2F + r] = s; return;
    }
    r -= 192;
    if (r < 12288) {                       // U1[i][k][j] = sum_m c1_w2[i][k][m]*lin1_w[(i*64+m)][j]
        int i = r / 4096, k = (r / 64) % 64, j = r % 64;
        float s = 0.f;
        for (int m = 0; m < 64; m++) s = fmaf(c1_w2[i * 4096 + k * 64 + m], lin1_w[(i * 64 + m) * 64 + j], s);
        fw[F_U1 + r] = s; return;
    }
    r -= 12288;
    if (r < 64) {                          // UB1
        float s = lin1_b[r];
        for (int i = 0; i < 3; i++)
            for (int m = 0; m < 64; m++) s = fmaf(c1_b2[i * 64 + m], lin1_w[(i * 64 + m) * 64 + r], s);
        fw[F_UB1 + r] = s; return;
    }
    r -= 64;
    if (r < 12288) {                       // U2
        int i = r / 4096, k = (r / 64) % 64, j = r % 64;
        float s = 0.f;
        for (int m = 0; m < 64; m++) s = fmaf(c2_w2[i * 4096 + k * 64 + m], lin2_w[(i * 64 + m) * 64 + j], s);
        fw[F_U2 + r] = s; return;
    }
    r -= 12288;
    {                                      // UB2
        float s = lin2_b[r];
        for (int i = 0; i < 3; i++)
            for (int m = 0; m < 64; m++) s = fmaf(c2_b2[i * 64 + m], lin2_w[(i * 64 + m) * 64 + r], s);
        fw[F_UB2 + r] = s; return;
    }
}

// ---------------- fold2: bf16 MFMA fragment weights (reads fold output) ----------------
// A-frag layout: m=lane&15, k=quad*8+j.  B-frag layout: n=lane&15, k=quad*8+j.
// k-permutation baked into V frags: t = 32*ka + 16*(j>>2) + 4*quad + (j&3).
__global__ __launch_bounds__(256) void fold2_kernel(
    const float* __restrict__ em1_w1, const float* __restrict__ em2_w1,
    const float* __restrict__ fw, unsigned short* __restrict__ fr)
{
    int idx = blockIdx.x * 256 + threadIdx.x;
    if (idx >= FOLD2_TOTAL) return;
    if (idx < 4096) {                       // W1^T A-frags for both layers, K padded to 32
        const float* w = (idx < 2048) ? em1_w1 : em2_w1;
        int r = idx & 2047;
        int tt = r >> 9, lane = (r >> 3) & 63, j = r & 7;
        int q = lane >> 4, k = q * 8 + j, m = tt * 16 + (lane & 15);
        fr[idx] = (k < 16) ? bf16u(w[k * 64 + m]) : (unsigned short)0;
        return;
    }
    if (idx < 10240) {                      // V1 B-frags [6][2][64][8]
        int r = idx - 4096;
        int nt = r / 1024, ka = (r >> 9) & 1, lane = (r >> 3) & 63, j = r & 7;
        int q = lane >> 4;
        int t = 32 * ka + 16 * (j >> 2) + 4 * q + (j & 3);
        int n = nt * 16 + (lane & 15);
        fr[idx] = bf16u(fw[F_V1H + t * 96 + n]);
        return;
    }
    {                                       // V2 B-frags [12][2][64][8]
        int r = idx - 10240;
        int nt = r / 1024, ka = (r >> 9) & 1, lane = (r >> 3) & 63, j = r & 7;
        int q = lane >> 4;
        int t = 32 * ka + 16 * (j >> 2) + 4 * q + (j & 3);
        int n = nt * 16 + (lane & 15);
        fr[idx] = bf16u(fw[F_V2H + t * 192 + n]);
        return;
    }
}

// ---------------- counting sort: hist -> scan -> scatter ----------------
__global__ __launch_bounds__(256) void hist_kernel(const int* __restrict__ ei, int* __restrict__ cnt) {
    int e = blockIdx.x * 256 + threadIdx.x;
    if (e < N_EDGES) atomicAdd(&cnt[ei[N_EDGES + e]], 1);
}

__global__ __launch_bounds__(256) void scan1_kernel(const int* __restrict__ cnt,
                                                    int* __restrict__ off, int* __restrict__ bsum) {
    __shared__ int sh[256];
    int t = threadIdx.x, i = blockIdx.x * 256 + t;
    int v = (i < N_NODES) ? cnt[i] : 0;
    sh[t] = v; __syncthreads();
    for (int d = 1; d < 256; d <<= 1) {
        int add = (t >= d) ? sh[t - d] : 0;
        __syncthreads();
        sh[t] += add;
        __syncthreads();
    }
    if (i < N_NODES) off[i] = sh[t] - v;     // exclusive
    if (t == 255) bsum[blockIdx.x] = sh[255];
}

__global__ __launch_bounds__(256) void scan2_kernel(int* __restrict__ bsum) {
    __shared__ int sh[256];
    int t = threadIdx.x;
    int v = (t < 196) ? bsum[t] : 0;
    sh[t] = v; __syncthreads();
    for (int d = 1; d < 256; d <<= 1) {
        int add = (t >= d) ? sh[t - d] : 0;
        __syncthreads();
        sh[t] += add;
        __syncthreads();
    }
    bsum[t] = sh[t] - v;                      // exclusive
}

__global__ __launch_bounds__(256) void scan3_kernel(int* __restrict__ off, const int* __restrict__ bsum,
                                                    int* __restrict__ cur) {
    int i = blockIdx.x * 256 + threadIdx.x;
    if (i < N_NODES) {
        int o = off[i] + bsum[i >> 8];
        off[i] = o;
        cur[i] = o;
    }
    if (i == 0) off[N_NODES] = N_EDGES;
}

__global__ __launch_bounds__(256) void scatter_kernel(const int* __restrict__ ei, int* __restrict__ cur,
                                                      int* __restrict__ ssrc, int* __restrict__ seid) {
    int e = blockIdx.x * 256 + threadIdx.x;
    if (e >= N_EDGES) return;
    int d = ei[N_EDGES + e];
    int p = atomicAdd(&cur[d], 1);
    ssrc[p] = ei[e];
    seid[p] = e;
}

// ---------------- MFMA edge projection ----------------
// Per 16-edge tile per wave:
//   GEMM1: T^T[t][e] = W1^T @ ea^T  (4 mfma, K=32 incl zero-pad; bias via C-init)
//   relu + pack straight into A-frags of GEMM2 (k-permutation, no cross-lane moves)
//   GEMM2: Q[e][n] = T @ V  (2*NT mfma; bias via C-init)
// Store: uint row-major [row=chunk-local edge][NT*8], uint(b*16+col) packs bf16
// cols (32b+col, 32b+col+16) -> coalesced 64B segments, zero write amplification.
template<int NT>
__global__ __launch_bounds__(256, 2) void edge_mfma_kernel(
    const float* __restrict__ edge_attr, const int* __restrict__ seid,
    const unsigned short* __restrict__ w1frag, const float* __restrict__ b1,
    const unsigned short* __restrict__ vfrag,  const float* __restrict__ bias2,
    unsigned int* __restrict__ qout, int tile0, int nTiles)
{
    const int lane = threadIdx.x & 63;
    const int wid  = threadIdx.x >> 6;
    const int col  = lane & 15;
    const int quad = lane >> 4;

    bf16x8 w1f[4];
#pragma unroll
    for (int tt = 0; tt < 4; tt++)
        w1f[tt] = *(const bf16x8*)(w1frag + (tt * 64 + lane) * 8);
    bf16x8 vf[NT][2];
#pragma unroll
    for (int nt = 0; nt < NT; nt++)
#pragma unroll
        for (int ka = 0; ka < 2; ka++)
            vf[nt][ka] = *(const bf16x8*)(vfrag + ((nt * 2 + ka) * 64 + lane) * 8);
    float4 b1v[4];
#pragma unroll
    for (int tt = 0; tt < 4; tt++)
        b1v[tt] = *(const float4*)(b1 + tt * 16 + quad * 4);
    float b2v[NT];
#pragma unroll
    for (int nt = 0; nt < NT; nt++) b2v[nt] = bias2[nt * 16 + col];

    const int gw = blockIdx.x * 4 + wid;
    const int stride = gridDim.x * 4;
    for (int t = gw; t < nTiles; t += stride) {
        const int s = (tile0 + t) * 16 + col;
        const int e = seid[s];
        bf16x8 eaf;
        uint4 eau = make_uint4(0u, 0u, 0u, 0u);
        if (quad < 2) {
            const float4 v0 = *(const float4*)(edge_attr + (size_t)e * 16 + quad * 8);
            const float4 v1 = *(const float4*)(edge_attr + (size_t)e * 16 + quad * 8 + 4);
            eau.x = packbf2(v0.x, v0.y); eau.y = packbf2(v0.z, v0.w);
            eau.z = packbf2(v1.x, v1.y); eau.w = packbf2(v1.z, v1.w);
        }
        eaf = __builtin_bit_cast(bf16x8, eau);

        f32x4 c1[4];
#pragma unroll
        for (int tt = 0; tt < 4; tt++) {
            f32x4 ci = {b1v[tt].x, b1v[tt].y, b1v[tt].z, b1v[tt].w};
            c1[tt] = __builtin_amdgcn_mfma_f32_16x16x32_bf16(w1f[tt], eaf, ci, 0, 0, 0);
        }

        bf16x8 a2[2];
#pragma unroll
        for (int ka = 0; ka < 2; ka++) {
            uint4 au;
            au.x = packbf2(fmaxf(c1[2 * ka][0], 0.f),     fmaxf(c1[2 * ka][1], 0.f));
            au.y = packbf2(fmaxf(c1[2 * ka][2], 0.f),     fmaxf(c1[2 * ka][3], 0.f));
            au.z = packbf2(fmaxf(c1[2 * ka + 1][0], 0.f), fmaxf(c1[2 * ka + 1][1], 0.f));
            au.w = packbf2(fmaxf(c1[2 * ka + 1][2], 0.f), fmaxf(c1[2 * ka + 1][3], 0.f));
            a2[ka] = __builtin_bit_cast(bf16x8, au);
        }

        f32x4 c2[NT];
#pragma unroll
        for (int nt = 0; nt < NT; nt++) {
            f32x4 ci = {b2v[nt], b2v[nt], b2v[nt], b2v[nt]};
            ci = __builtin_amdgcn_mfma_f32_16x16x32_bf16(a2[0], vf[nt][0], ci, 0, 0, 0);
            c2[nt] = __builtin_amdgcn_mfma_f32_16x16x32_bf16(a2[1], vf[nt][1], ci, 0, 0, 0);
        }

        const size_t rowb = (size_t)t * 16 + quad * 4;
#pragma unroll
        for (int b = 0; b < NT / 2; b++) {
#pragma unroll
            for (int r = 0; r < 4; r++) {
                unsigned int u = packbf2(c2[2 * b][r], c2[2 * b + 1][r]);
                qout[(rowb + r) * (size_t)(NT * 8) + b * 16 + col] = u;
            }
        }
    }
}

// ---------------- gather + node MLP, layer 1 ----------------
// q1 uint ui=l (l<48): cols (n1 = (l>>4)*32 + (l&15), n2 = n1+16); x-feature = n%32.
__global__ __launch_bounds__(64) void gather_node1_kernel(
    const float* __restrict__ x, const int* __restrict__ off, const int* __restrict__ ssrc,
    const unsigned int* __restrict__ q1,
    const float* __restrict__ c1_w1, const float* __restrict__ c1_b1,
    const float* __restrict__ fw, float* __restrict__ h1)
{
    __shared__ float inb[96];
    __shared__ float zl[64];
    const int n = blockIdx.x, l = threadIdx.x;
    const int s0 = off[n], s1 = off[n + 1];

    if (l < 48) {
        const int c = l & 15;
        const int n1 = (l >> 4) * 32 + c, n2 = n1 + 16;
        float a0 = 0.f, a1 = 0.f;
        for (int s = s0; s < s1; s++) {
            const int src = ssrc[s];
            const unsigned int u = q1[(size_t)s * 48 + l];
            a0 += fmaxf(x[(size_t)src * 32 + c] + bflo(u), 0.f);
            a1 += fmaxf(x[(size_t)src * 32 + c + 16] + bfhi(u), 0.f);
        }
        inb[n1] = x[(size_t)n * 32 + c] + a0;
        inb[n2] = x[(size_t)n * 32 + c + 16] + a1;
    }
    __syncthreads();

    const float* U1  = fw + F_U1;
    float acc = fw[F_UB1 + l];
    for (int i = 0; i < 3; i++) {
        float z = c1_b1[i * 64 + l];
#pragma unroll
        for (int k = 0; k < 32; k++) z = fmaf(inb[i * 32 + k], c1_w1[i * 2048 + k * 64 + l], z);
        zl[l] = fmaxf(z, 0.f);
        __syncthreads();
#pragma unroll
        for (int k = 0; k < 64; k++) acc = fmaf(zl[k], U1[i * 4096 + k * 64 + l], acc);
        __syncthreads();
    }
    h1[(size_t)n * 64 + l] = fmaxf(acc, 0.f);
}

// ---------------- gather layer 2 (chunked; chunk0 writes, chunk1 accumulates) ----------------
// q2 uint ui: cols (32*(ui>>4)+(ui&15), +16); h-feature k = col%64.  Lane l handles
// ui=l and (l<32) ui=64+l; both share k1 = ((l>>4)&1)*32 + (l&15).
// agg2 kept in PERMUTED order: float2 slot 2*ui = (colA, colA+16) sums.
__global__ __launch_bounds__(64) void gather2_kernel(
    const float* __restrict__ h1, const int* __restrict__ off, const int* __restrict__ ssrc,
    const unsigned int* __restrict__ q2, float* __restrict__ agg2, int lo, int hi, int first)
{
    const int n = blockIdx.x, l = threadIdx.x;
    int s0 = off[n], s1 = off[n + 1];
    if (s0 < lo) s0 = lo;
    if (s1 > hi) s1 = hi;
    if (!first && s0 >= s1) return;

    const int k1 = ((l >> 4) & 1) * 32 + (l & 15);
    float a0 = 0.f, a1 = 0.f, b0 = 0.f, b1 = 0.f;
    for (int s = s0; s < s1; s++) {
        const int src = ssrc[s];
        const float hv0 = h1[(size_t)src * 64 + k1];
        const float hv1 = h1[(size_t)src * 64 + k1 + 16];
        const unsigned int u = q2[(size_t)(s - lo) * 96 + l];
        a0 += fmaxf(hv0 + bflo(u), 0.f);
        a1 += fmaxf(hv1 + bfhi(u), 0.f);
        if (l < 32) {
            const unsigned int u2 = q2[(size_t)(s - lo) * 96 + 64 + l];
            b0 += fmaxf(hv0 + bflo(u2), 0.f);
            b1 += fmaxf(hv1 + bfhi(u2), 0.f);
        }
    }
    float2* ap = (float2*)(agg2 + (size_t)n * 192 + 2 * l);
    float2* bp = (float2*)(agg2 + (size_t)n * 192 + 128 + 2 * l);
    if (first) {
        *ap = make_float2(a0, a1);
        if (l < 32) *bp = make_float2(b0, b1);
    } else {
        float2 av = *ap; av.x += a0; av.y += a1; *ap = av;
        if (l < 32) { float2 bv = *bp; bv.x += b0; bv.y += b1; *bp = bv; }
    }
}

// ---------------- node MLP layer 2 (un-permutes agg2 into true col order) ----------------
__global__ __launch_bounds__(64) void node2_kernel(
    const float* __restrict__ h1, const float* __restrict__ agg2,
    const float* __restrict__ c2_w1, const float* __restrict__ c2_b1,
    const float* __restrict__ fw, float* __restrict__ h2)
{
    __shared__ float inb[192];
    __shared__ float zl[64];
    const int n = blockIdx.x, l = threadIdx.x;
    const int k1 = ((l >> 4) & 1) * 32 + (l & 15);
    const int nA = (l >> 4) * 32 + (l & 15), nB = nA + 16;
    const float hk1 = h1[(size_t)n * 64 + k1];
    const float hk2 = h1[(size_t)n * 64 + k1 + 16];
    const float2 f2 = *(const float2*)(agg2 + (size_t)n * 192 + 2 * l);
    inb[nA] = hk1 + f2.x;
    inb[nB] = hk2 + f2.y;
    if (l < 32) {
        const float2 f2b = *(const float2*)(agg2 + (size_t)n * 192 + 128 + 2 * l);
        inb[128 + nA] = hk1 + f2b.x;
        inb[128 + nB] = hk2 + f2b.y;
    }
    __syncthreads();

    const float* U2 = fw + F_U2;
    float acc = fw[F_UB2 + l];
    for (int i = 0; i < 3; i++) {
        float z = c2_b1[i * 64 + l];
#pragma unroll
        for (int k = 0; k < 64; k++) z = fmaf(inb[i * 64 + k], c2_w1[i * 4096 + k * 64 + l], z);
        zl[l] = fmaxf(z, 0.f);
        __syncthreads();
#pragma unroll
        for (int k = 0; k < 64; k++) acc = fmaf(zl[k], U2[i * 4096 + k * 64 + l], acc);
        __syncthreads();
    }
    h2[(size_t)n * 64 + l] = fmaxf(acc, 0.f);
}

// ---------------- pooling (batch is sorted: binary-search graph bounds) ----------------
__global__ __launch_bounds__(256) void pool_kernel(
    const float* __restrict__ h2, const int* __restrict__ batch,
    float* __restrict__ gsum, float* __restrict__ gcnt)
{
    __shared__ float red[256];
    const int g = blockIdx.x, t = threadIdx.x;
    int lo = 0, hi = N_NODES;
    while (lo < hi) { int m = (lo + hi) >> 1; if (batch[m] < g) lo = m + 1; else hi = m; }
    int lo2 = lo, hi2 = N_NODES;
    while (lo2 < hi2) { int m = (lo2 + hi2) >> 1; if (batch[m] < g + 1) lo2 = m + 1; else hi2 = m; }

    const int col = t & 63, ch = t >> 6;
    float s = 0.f;
    for (int idx = lo + ch; idx < lo2; idx += 4) s += h2[(size_t)idx * 64 + col];
    red[t] = s;
    __syncthreads();
    if (t < 64) gsum[(size_t)g * 64 + t] = red[t] + red[64 + t] + red[128 + t] + red[192 + t];
    if (t == 0) gcnt[g] = (float)(lo2 - lo);
}

// ---------------- final: mean-pool divide + fc ----------------
__global__ __launch_bounds__(256) void final_kernel(
    const float* __restrict__ gsum, const float* __restrict__ gcnt,
    const float* __restrict__ u, const float* __restrict__ fc_w,
    const float* __restrict__ fc_b, float* __restrict__ out)
{
    int g = blockIdx.x * 256 + threadIdx.x;
    if (g >= N_GRAPHS) return;
    float inv = 1.f / fmaxf(gcnt[g], 1.f);
    float s = fc_b[0];
#pragma unroll
    for (int j = 0; j < 64; j++) s = fmaf(gsum[(size_t)g * 64 + j] * inv, fc_w[j], s);
#pragma unroll
    for (int k = 0; k < 32; k++) s = fmaf(u[(size_t)g * 32 + k], fc_w[64 + k], s);
    out[g] = s;
}

extern "C" void kernel_launch(void* const* d_in, const int* in_sizes, int n_in,
                              void* d_out, int out_size, void* d_ws, size_t ws_size,
                              hipStream_t stream) {
    (void)in_sizes; (void)n_in; (void)out_size; (void)ws_size;
    const float* x        = (const float*)d_in[0];
    const float* edge_attr= (const float*)d_in[1];
    const float* u        = (const float*)d_in[2];
    const float* em1_w1   = (const float*)d_in[3];
    const float* em1_b1   = (const float*)d_in[4];
    const float* em1_w2   = (const float*)d_in[5];
    const float* em1_b2   = (const float*)d_in[6];
    const float* em2_w1   = (const float*)d_in[7];
    const float* em2_b1   = (const float*)d_in[8];
    const float* em2_w2   = (const float*)d_in[9];
    const float* em2_b2   = (const float*)d_in[10];
    const float* c1_lin_w = (const float*)d_in[11];
    const float* c1_lin_b = (const float*)d_in[12];
    const float* c1_w1    = (const float*)d_in[13];
    const float* c1_b1    = (const float*)d_in[14];
    const float* c1_w2    = (const float*)d_in[15];
    const float* c1_b2    = (const float*)d_in[16];
    const float* c2_lin_w = (const float*)d_in[17];
    const float* c2_lin_b = (const float*)d_in[18];
    const float* c2_w1    = (const float*)d_in[19];
    const float* c2_b1    = (const float*)d_in[20];
    const float* c2_w2    = (const float*)d_in[21];
    const float* c2_b2    = (const float*)d_in[22];
    const float* lin1_w   = (const float*)d_in[23];
    const float* lin1_b   = (const float*)d_in[24];
    const float* lin2_w   = (const float*)d_in[25];
    const float* lin2_b   = (const float*)d_in[26];
    const float* fc_w     = (const float*)d_in[27];
    const float* fc_b     = (const float*)d_in[28];
    const int*   ei       = (const int*)d_in[29];
    const int*   batch    = (const int*)d_in[30];

    char* wsb = (char*)d_ws;
    int*   cnt  = (int*)(wsb + B_CNT);
    int*   off  = (int*)(wsb + B_OFF);
    int*   cur  = (int*)(wsb + B_CUR);
    int*   bsum = (int*)(wsb + B_BSUM);
    int*   ssrc = (int*)(wsb + B_SSRC);
    int*   seid = (int*)(wsb + B_SEID);
    float* gsum = (float*)(wsb + B_GSUM);
    float* gcnt = (float*)(wsb + B_GCNT);
    float* agg2 = (float*)(wsb + B_AGG2);
    unsigned int* q = (unsigned int*)(wsb + B_Q);
    float* h1   = (float*)(wsb + B_H1);
    float* h2   = (float*)(wsb + B_H2);
    float* fw   = (float*)(wsb + B_FOLD);
    unsigned short* fr = (unsigned short*)(wsb + B_FRAG);
    float* out  = (float*)d_out;

    (void)hipMemsetAsync(d_ws, 0, ZERO_BYTES, stream);   // histogram counters only

    fold_kernel<<<(FOLD_TOTAL + 255) / 256, 256, 0, stream>>>(
        em1_w2, em1_b2, em2_w2, em2_b2, c1_lin_w, c1_lin_b, c2_lin_w, c2_lin_b,
        c1_w2, c1_b2, c2_w2, c2_b2, lin1_w, lin1_b, lin2_w, lin2_b, fw);
    fold2_kernel<<<(FOLD2_TOTAL + 255) / 256, 256, 0, stream>>>(em1_w1, em2_w1, fw, fr);

    // counting sort by dst
    hist_kernel<<<N_EDGES / 256, 256, 0, stream>>>(ei, cnt);
    scan1_kernel<<<196, 256, 0, stream>>>(cnt, off, bsum);
    scan2_kernel<<<1, 256, 0, stream>>>(bsum);
    scan3_kernel<<<196, 256, 0, stream>>>(off, bsum, cur);
    scatter_kernel<<<N_EDGES / 256, 256, 0, stream>>>(ei, cur, ssrc, seid);

    // layer 1: edge MFMA (NT=6, 50000 tiles) + gather/node
    edge_mfma_kernel<6><<<512, 256, 0, stream>>>(
        edge_attr, seid, fr + FR_W1E1, em1_b1, fr + FR_V1, fw + F_B1F, q, 0, N_EDGES / 16);
    gather_node1_kernel<<<N_NODES, 64, 0, stream>>>(x, off, ssrc, q, c1_w1, c1_b1, fw, h1);

    // layer 2 (two chunks, q buffer reused)
    for (int c = 0; c < 2; c++) {
        const int lo = c * ECHUNK, hi = lo + ECHUNK;
        edge_mfma_kernel<12><<<512, 256, 0, stream>>>(
            edge_attr, seid, fr + FR_W1E2, em2_b1, fr + FR_V2, fw + F_B2F, q,
            lo / 16, ECHUNK / 16);
        gather2_kernel<<<N_NODES, 64, 0, stream>>>(h1, off, ssrc, q, agg2, lo, hi, c == 0 ? 1 : 0);
    }
    node2_kernel<<<N_NODES, 64, 0, stream>>>(h1, agg2, c2_w1, c2_b1, fw, h2);

    // pooling + head
    pool_kernel<<<N_GRAPHS, 256, 0, stream>>>(h2, batch, gsum, gcnt);
    final_kernel<<<(N_GRAPHS + 255) / 256, 256, 0, stream>>>(gsum, gcnt, u, fc_w, fc_b, out);
}